// Round 16
// baseline (631.436 us; speedup 1.0000x reference)
//
#include <hip/hip_runtime.h>
#include <hip/hip_bf16.h>
#include <stdint.h>

// ---------------------------------------------------------------------------
// PFGAT. R16: k_mix bilinear reduction — node attention's k2/v2 GEMMs are
// algebraically eliminated: scr[m] = z7·M·z2[m] + vk·z2[m] + vq·z7 + bqbk
// with M = s_wq@s_wk^T precomputed once (k_prep); ctx2 = zbar@s_wv + bv.
// Per-thread FMAs 2816->~950, broadcast LDS reads halved. Rest = R15.
// ---------------------------------------------------------------------------

#define BB     4
#define TT     8
#define NN     2048
#define FIN    16
#define HID    128
#define BM     (BB*TT)            // 32 attention slices
#define PROWS  (BM*NN)            // 65536 rows
#define NHEADS 4
#define OUTCH  64
#define OUTF   14
#define NEDGE  32768
#define NEDGEB (NEDGE*BB)         // 131072
#define NNODE  (BB*NN)            // 8192
#define NETOT  (NEDGEB + NNODE)   // 139264 (edges + self loops)

#define TQ     64                 // query tile (rows per block)
#define NTILE  (NN/TQ)            // 32 query tiles per slice

typedef __hip_bfloat16 bf16;
typedef __attribute__((ext_vector_type(8))) short bf16x8;   // MFMA A/B frag
typedef __attribute__((ext_vector_type(4))) float f32x4;    // MFMA C/D frag

__device__ __forceinline__ float b2f(bf16 v){ return __bfloat162float(v); }
__device__ __forceinline__ bf16  f2b(float f){ return __float2bfloat16(f); }

// ---------------------------------------------------------------------------
// K1: per row: LN1 over F=16 -> k,v projections; K row-major, V key-tiled.
// ---------------------------------------------------------------------------
__global__ void k_kv(const float* __restrict__ x,
                     const float* __restrict__ g1, const float* __restrict__ bb1,
                     const float* __restrict__ wk, const float* __restrict__ bk,
                     const float* __restrict__ wv, const float* __restrict__ bv,
                     int in_off, bf16* __restrict__ K, bf16* __restrict__ Vt)
{
    const int rloc = blockIdx.x;
    const int rin  = rloc + in_off;
    const int h = threadIdx.x;       // 0..127
    __shared__ float xr[FIN], lnv[FIN];
    if (h < FIN) xr[h] = x[(size_t)rin*FIN + h];
    __syncthreads();
    float mu = 0.f;
    #pragma unroll
    for (int f = 0; f < FIN; ++f) mu += xr[f];
    mu *= (1.f/FIN);
    float var = 0.f;
    #pragma unroll
    for (int f = 0; f < FIN; ++f){ float d = xr[f]-mu; var += d*d; }
    var *= (1.f/FIN);
    const float inv = rsqrtf(var + 1e-5f);
    if (h < FIN) lnv[h] = (xr[h]-mu)*inv*g1[h] + bb1[h];
    __syncthreads();
    float ak = bk[h], av = bv[h];
    #pragma unroll
    for (int f = 0; f < FIN; ++f){
        const float l = lnv[f];
        ak += l * wk[f*HID + h];
        av += l * wv[f*HID + h];
    }
    K[(size_t)rloc*HID + h] = f2b(ak);
    const int slice = rloc >> 11;            // 0 in narrow mode
    const int key   = rloc & (NN-1);
    Vt[(((size_t)slice*(NN/32) + (key>>5))*HID + h)*32 + (key&31)] = f2b(av);
}

// ---------------------------------------------------------------------------
// K2 (MFMA flash): unchanged from R15.
// ---------------------------------------------------------------------------
__global__ __launch_bounds__(256)
void k_attn_mfma(const float* __restrict__ x,
                 const bf16* __restrict__ K, const bf16* __restrict__ Vt,
                 const float* __restrict__ g1, const float* __restrict__ bb1,
                 const float* __restrict__ wq, const float* __restrict__ bq,
                 int slice_off, bf16* __restrict__ CX)
{
    const int tile  = (NTILE-1) - (int)blockIdx.y;   // big tiles first
    const int q0    = tile*TQ;
    const int slice = blockIdx.x + slice_off;
    const int t     = threadIdx.x;
    const int w     = t >> 6;
    const int lane  = t & 63;
    const int quad  = lane >> 4;
    const int l16   = lane & 15;
    const int wr0   = w*16;

    __shared__ float xs [TQ][FIN];
    __shared__ bf16  Qs [TQ][136];
    __shared__ bf16  Ps [4][16][40];
    __shared__ bf16  Ks [32*136];
    __shared__ bf16  Vs [128*40];

    for (int u = t; u < TQ*FIN; u += 256)
        ((float*)xs)[u] = x[((size_t)slice*NN + q0)*FIN + u];
    __syncthreads();
    if (t < TQ){
        float mu = 0.f;
        #pragma unroll
        for (int f = 0; f < FIN; ++f) mu += xs[t][f];
        mu *= (1.f/FIN);
        float var = 0.f;
        #pragma unroll
        for (int f = 0; f < FIN; ++f){ float d = xs[t][f]-mu; var += d*d; }
        var *= (1.f/FIN);
        const float inv = rsqrtf(var + 1e-5f);
        #pragma unroll
        for (int f = 0; f < FIN; ++f)
            xs[t][f] = (xs[t][f]-mu)*inv*g1[f] + bb1[f];
    }
    __syncthreads();
    {
        const int ch = t & 127, half = t >> 7;
        const float scale = 0.08838834764831845f;
        float wqr[FIN];
        #pragma unroll
        for (int f = 0; f < FIN; ++f) wqr[f] = wq[f*HID + ch];
        const float bqv = bq[ch];
        for (int j = 0; j < 32; ++j){
            const int row = half*32 + j;
            const float4 l0 = ((const float4*)&xs[row][0])[0];
            const float4 l1 = ((const float4*)&xs[row][0])[1];
            const float4 l2 = ((const float4*)&xs[row][0])[2];
            const float4 l3 = ((const float4*)&xs[row][0])[3];
            float a = bqv;
            a += l0.x*wqr[0]  + l0.y*wqr[1]  + l0.z*wqr[2]  + l0.w*wqr[3];
            a += l1.x*wqr[4]  + l1.y*wqr[5]  + l1.z*wqr[6]  + l1.w*wqr[7];
            a += l2.x*wqr[8]  + l2.y*wqr[9]  + l2.z*wqr[10] + l2.w*wqr[11];
            a += l3.x*wqr[12] + l3.y*wqr[13] + l3.z*wqr[14] + l3.w*wqr[15];
            Qs[row][ch] = f2b(a*scale);
        }
    }
    __syncthreads();

    bf16x8 qf[4];
    #pragma unroll
    for (int ks = 0; ks < 4; ++ks)
        qf[ks] = *(const bf16x8*)(const void*)&Qs[wr0 + l16][ks*32 + quad*8];

    f32x4 O[8];
    #pragma unroll
    for (int ct = 0; ct < 8; ++ct) O[ct] = (f32x4){0.f,0.f,0.f,0.f};
    float l_[4] = {0.f,0.f,0.f,0.f};

    const size_t kb = (size_t)blockIdx.x * NN * HID;
    const size_t vb = (size_t)blockIdx.x * (size_t)(NN/32) * HID*32;
    const int jend_blk = q0 + TQ - 1;
    const int my_jmax  = q0 + wr0 + 15;
    const int brow = q0 + wr0 + quad*4;

    for (int j0 = 0; j0 <= jend_blk; j0 += 32){
        {
            const bf16* ksl = K  + kb + (size_t)j0*HID;
            const bf16* vsl = Vt + vb + (size_t)(j0>>5)*(HID*32);
            #pragma unroll
            for (int it = 0; it < 2; ++it){
                const int c = t + it*256;
                *(bf16x8*)(void*)&Ks[(c>>4)*136 + (c&15)*8] =
                    *(const bf16x8*)(const void*)(ksl + c*8);
                *(bf16x8*)(void*)&Vs[(c>>2)*40 + (c&3)*8] =
                    *(const bf16x8*)(const void*)(vsl + c*8);
            }
        }
        __syncthreads();

        if (j0 <= my_jmax){
            f32x4 S0 = (f32x4){0.f,0.f,0.f,0.f}, S1 = S0;
            #pragma unroll
            for (int ks = 0; ks < 4; ++ks){
                const bf16x8 kf0 = *(const bf16x8*)(const void*)
                    &Ks[(l16     )*136 + ks*32 + quad*8];
                const bf16x8 kf1 = *(const bf16x8*)(const void*)
                    &Ks[(l16 + 16)*136 + ks*32 + quad*8];
                S0 = __builtin_amdgcn_mfma_f32_16x16x32_bf16(qf[ks], kf0, S0, 0, 0, 0);
                S1 = __builtin_amdgcn_mfma_f32_16x16x32_bf16(qf[ks], kf1, S1, 0, 0, 0);
            }
            const int c0j = j0 + l16, c1j = c0j + 16;
            #pragma unroll
            for (int r = 0; r < 4; ++r){
                const float s0 = (c0j <= brow + r) ? S0[r] : -1e30f;
                const float s1 = (c1j <= brow + r) ? S1[r] : -1e30f;
                const bf16 hb0 = f2b(__expf(s0));
                const bf16 hb1 = f2b(__expf(s1));
                Ps[w][quad*4 + r][l16]      = hb0;
                Ps[w][quad*4 + r][l16 + 16] = hb1;
                l_[r] += b2f(hb0) + b2f(hb1);
            }
            const bf16x8 pf = *(const bf16x8*)(const void*)&Ps[w][l16][quad*8];
            #pragma unroll
            for (int ct = 0; ct < 8; ++ct){
                const bf16x8 vf = *(const bf16x8*)(const void*)
                    &Vs[(ct*16 + l16)*40 + quad*8];
                O[ct] = __builtin_amdgcn_mfma_f32_16x16x32_bf16(pf, vf, O[ct], 0, 0, 0);
            }
        }
        __syncthreads();
    }

    {
        float inv[4];
        #pragma unroll
        for (int r = 0; r < 4; ++r){
            float rs = l_[r];
            rs += __shfl_xor(rs, 1);
            rs += __shfl_xor(rs, 2);
            rs += __shfl_xor(rs, 4);
            rs += __shfl_xor(rs, 8);
            inv[r] = 1.f/rs;
        }
        #pragma unroll
        for (int ct = 0; ct < 8; ++ct)
        #pragma unroll
        for (int r = 0; r < 4; ++r)
            Qs[wr0 + quad*4 + r][ct*16 + l16] = f2b(O[ct][r]*inv[r]);
    }
    __syncthreads();
    {
        const int row = t >> 2, ch0 = (t & 3)*32;
        bf16* dst = CX + ((size_t)slice*NN + q0 + row)*HID + ch0;
        #pragma unroll
        for (int c = 0; c < 4; ++c)
            *(bf16x8*)(void*)(dst + c*8) =
                *(const bf16x8*)(const void*)&Qs[row][ch0 + c*8];
    }
}

// ---------------------------------------------------------------------------
// K_H1 (MFMA epilogue GEMM): unchanged from R15.
// ---------------------------------------------------------------------------
__global__ __launch_bounds__(256)
void k_h1(const float* __restrict__ x,
          const float* __restrict__ t_wo, const float* __restrict__ skw,
          const float* __restrict__ t_bo, const float* __restrict__ skb,
          int slice_off, bf16* __restrict__ CXH1)
{
    const int slice = blockIdx.x + slice_off;
    const int q0    = blockIdx.y * TQ;
    const int t     = threadIdx.x;
    const int w     = t >> 6;
    const int lane  = t & 63;
    const int quad  = lane >> 4;
    const int l16   = lane & 15;
    const int wr0   = w*16;

    __shared__ bf16 Aext[TQ][168];
    __shared__ bf16 Bext[HID][168];

    {
        const bf16* src = CXH1 + ((size_t)slice*NN + q0)*HID;
        #pragma unroll
        for (int it = 0; it < 4; ++it){
            const int c = t + it*256;
            *(bf16x8*)(void*)&Aext[c>>4][(c&15)*8] =
                *(const bf16x8*)(const void*)(src + c*8);
        }
    }
    #pragma unroll
    for (int it = 0; it < 4; ++it){
        const int u = t + it*256;
        const int row = u >> 4, f = u & 15;
        Aext[row][128 + f] = f2b(x[((size_t)slice*NN + q0 + row)*FIN + f]);
    }
    #pragma unroll
    for (int it = 0; it < 4; ++it){
        const int u = t + it*256;
        Aext[u>>4][144 + (u&15)] = f2b(0.f);
    }
    #pragma unroll
    for (int it = 0; it < 16; ++it){
        const int idx = t + it*256;
        const int c = idx >> 5, ch4 = (idx & 31)*4;
        const float4 v = ((const float4*)t_wo)[idx];
        Bext[ch4+0][c] = f2b(v.x);
        Bext[ch4+1][c] = f2b(v.y);
        Bext[ch4+2][c] = f2b(v.z);
        Bext[ch4+3][c] = f2b(v.w);
    }
    #pragma unroll
    for (int it = 0; it < 2; ++it){
        const int idx = t + it*256;
        const int f = idx >> 5, ch4 = (idx & 31)*4;
        const float4 v = ((const float4*)skw)[idx];
        Bext[ch4+0][128+f] = f2b(v.x);
        Bext[ch4+1][128+f] = f2b(v.y);
        Bext[ch4+2][128+f] = f2b(v.z);
        Bext[ch4+3][128+f] = f2b(v.w);
    }
    #pragma unroll
    for (int it = 0; it < 8; ++it){
        const int u = t + it*256;
        Bext[u>>4][144 + (u&15)] = f2b(0.f);
    }
    __syncthreads();

    f32x4 O[8];
    #pragma unroll
    for (int ct = 0; ct < 8; ++ct) O[ct] = (f32x4){0.f,0.f,0.f,0.f};
    #pragma unroll
    for (int ks = 0; ks < 5; ++ks){
        const bf16x8 af = *(const bf16x8*)(const void*)&Aext[wr0 + l16][ks*32 + quad*8];
        #pragma unroll
        for (int ct = 0; ct < 8; ++ct){
            const bf16x8 bf = *(const bf16x8*)(const void*)&Bext[ct*16 + l16][ks*32 + quad*8];
            O[ct] = __builtin_amdgcn_mfma_f32_16x16x32_bf16(af, bf, O[ct], 0, 0, 0);
        }
    }
    #pragma unroll
    for (int ct = 0; ct < 8; ++ct){
        const int col = ct*16 + l16;
        const float bias = t_bo[col] + skb[col];
        #pragma unroll
        for (int r = 0; r < 4; ++r)
            Aext[wr0 + quad*4 + r][col] = f2b(O[ct][r] + bias);
    }
    __syncthreads();
    {
        const int row = t >> 2, ch0 = (t & 3)*32;
        bf16* dst = CXH1 + ((size_t)slice*NN + q0 + row)*HID + ch0;
        #pragma unroll
        for (int c = 0; c < 4; ++c)
            *(bf16x8*)(void*)(dst + c*8) =
                *(const bf16x8*)(const void*)&Aext[row][ch0 + c*8];
    }
}

// ---------------------------------------------------------------------------
// K_PREP: M[a][c] = sum_h s_wq[a][h]*s_wk[c][h]  (128x128, fp32).
// 16 blocks x 256 thr; block b does a-rows 8b..8b+7; s_wk staged in LDS.
// ---------------------------------------------------------------------------
__global__ __launch_bounds__(256)
void k_prep(const float* __restrict__ s_wq, const float* __restrict__ s_wk,
            float* __restrict__ M)
{
    const int b = blockIdx.x;          // 0..15
    const int t = threadIdx.x;
    __shared__ float wk[HID*HID];      // 64 KB
    __shared__ float wq[8][HID];       // 4 KB
    for (int u = t; u < HID*HID; u += 256) wk[u] = s_wk[u];
    for (int u = t; u < 8*HID;   u += 256) ((float*)wq)[u] = s_wq[b*8*HID + u];
    __syncthreads();
    #pragma unroll
    for (int i = 0; i < 4; ++i){
        const int e = t + i*256;       // 0..1023
        const int a = e >> 7, c = e & 127;
        float acc = 0.f;
        for (int h = 0; h < HID; ++h) acc += wq[a][h]*wk[c*HID + h];
        M[(size_t)(b*8 + a)*HID + c] = acc;
    }
}

// vk[c] = bq . s_wk[c][:], vq[a] = s_wq[a][:] . bk, sbb = bq.bk
__global__ void k_prep2(const float* __restrict__ s_wq, const float* __restrict__ s_wk,
                        const float* __restrict__ bq, const float* __restrict__ bk,
                        float* __restrict__ vk, float* __restrict__ vq,
                        float* __restrict__ sbb)
{
    const int t = threadIdx.x;         // 128
    float a1 = 0.f, a2 = 0.f;
    for (int h = 0; h < HID; ++h){
        a1 += bq[h]*s_wk[t*HID + h];
        a2 += s_wq[t*HID + h]*bk[h];
    }
    vk[t] = a1; vq[t] = a2;
    if (t == 0){
        float s = 0.f;
        for (int h = 0; h < HID; ++h) s += bq[h]*bk[h];
        *sbb = s;
    }
}

// ---------------------------------------------------------------------------
// K3 (R16): bilinear node attention. 4 nodes/block (512 thr).
// scr[m] = (z7@M + vk).z2[m] + vq.z7 + sbb, ctx2 = zbar@s_wv + bv.
// ---------------------------------------------------------------------------
__global__ __launch_bounds__(512)
void k_mix(const bf16* __restrict__ H1,
           const float* __restrict__ ln2g, const float* __restrict__ ln2b,
           const float* __restrict__ M, const float* __restrict__ vk,
           const float* __restrict__ vq, const float* __restrict__ sbbp,
           const float* __restrict__ s_bv, const float* __restrict__ s_wv,
           const float* __restrict__ s_wo, const float* __restrict__ s_bo,
           const float* __restrict__ ln3g, const float* __restrict__ ln3b,
           const float* __restrict__ w1, const float* __restrict__ bm1,
           const float* __restrict__ w2, const float* __restrict__ bm2,
           float* __restrict__ Hn)
{
    const int g  = threadIdx.x >> 7;          // node slot 0..3
    const int h  = threadIdx.x & 127;
    const int blk = blockIdx.x*4 + g;         // b*NN + s
    const int b = blk >> 11, s = blk & (NN-1);

    __shared__ float h1[4][TT][HID], z2[4][TT][HID];
    __shared__ float rp[4][HID], zb[4][HID], cx2[4][HID], z3s[4][HID];
    __shared__ float hls[4][2*HID];
    __shared__ float scr[4][TT];
    __shared__ float mu_s[4][TT], inv_s[4][TT];
    __shared__ float redA[4][2];              // [g][wave-in-group]

    #pragma unroll
    for (int m = 0; m < TT; ++m)
        h1[g][m][h] = b2f(H1[((size_t)(b*TT + m)*NN + s)*HID + h]);
    __syncthreads();

    // ---- LN2 stats: all 8 m in parallel (16-lane shfl groups) ----
    {
        const int m = h >> 4, l16 = h & 15;
        float sum = 0.f, sq = 0.f;
        #pragma unroll
        for (int j = 0; j < 8; ++j){
            const float v = h1[g][m][l16 + 16*j];
            sum += v; sq += v*v;
        }
        sum += __shfl_xor(sum, 1); sq += __shfl_xor(sq, 1);
        sum += __shfl_xor(sum, 2); sq += __shfl_xor(sq, 2);
        sum += __shfl_xor(sum, 4); sq += __shfl_xor(sq, 4);
        sum += __shfl_xor(sum, 8); sq += __shfl_xor(sq, 8);
        if (l16 == 0){
            const float mu = sum*(1.f/HID);
            const float var = sq*(1.f/HID) - mu*mu;
            mu_s[g][m] = mu;
            inv_s[g][m] = rsqrtf(var + 1e-5f);
        }
    }
    __syncthreads();
    {
        const float g2v = ln2g[h], b2v = ln2b[h];
        #pragma unroll
        for (int m = 0; m < TT; ++m)
            z2[g][m][h] = (h1[g][m][h] - mu_s[g][m])*inv_s[g][m]*g2v + b2v;
    }
    __syncthreads();

    // ---- rp = z7@M + vk (coalesced M); sbq partial = vq[h]*z7[h] ----
    {
        float r = vk[h];
        for (int a = 0; a < HID; ++a) r += z2[g][TT-1][a]*M[a*HID + h];
        rp[g][h] = r;
        float p = vq[h]*z2[g][TT-1][h];
        #pragma unroll
        for (int off = 1; off < 64; off <<= 1) p += __shfl_xor(p, off);
        const int wv = (threadIdx.x >> 6) & 1;
        if ((threadIdx.x & 63) == 0) redA[g][wv] = p;
    }
    __syncthreads();

    // ---- scr[m] = rp . z2[m] + sbq + sbb (16-lane shfl groups) ----
    {
        const int m = h >> 4, l16 = h & 15;
        float d = 0.f;
        #pragma unroll
        for (int j = 0; j < 8; ++j){
            const int c = l16 + 16*j;
            d += rp[g][c]*z2[g][m][c];
        }
        d += __shfl_xor(d, 1);
        d += __shfl_xor(d, 2);
        d += __shfl_xor(d, 4);
        d += __shfl_xor(d, 8);
        if (l16 == 0){
            const float sbq = redA[g][0] + redA[g][1];
            scr[g][m] = (d + sbq + *sbbp) * 0.08838834764831845f;
        }
    }
    __syncthreads();

    // ---- softmax over 8 slots (per-thread) + zbar ----
    {
        float mx = -1e30f;
        #pragma unroll
        for (int m = 0; m < TT; ++m) mx = fmaxf(mx, scr[g][m]);
        float p[TT], se = 0.f;
        #pragma unroll
        for (int m = 0; m < TT; ++m){ p[m] = __expf(scr[g][m]-mx); se += p[m]; }
        const float isum = 1.f/se;
        float zz = 0.f;
        #pragma unroll
        for (int m = 0; m < TT; ++m) zz += p[m]*z2[g][m][h];
        zb[g][h] = zz*isum;
    }
    __syncthreads();

    // ---- ctx2 = zbar@s_wv + bv ----
    {
        float a = s_bv[h];
        for (int c = 0; c < HID; ++c) a += zb[g][c]*s_wv[c*HID + h];
        cx2[g][h] = a;
    }
    __syncthreads();

    // ---- o = ctx2@s_wo + bo; h2; LN3 ----
    float o = s_bo[h];
    for (int c = 0; c < HID; ++c) o += cx2[g][c]*s_wo[c*HID + h];
    const float h2 = h1[g][TT-1][h] + o;

    {
        float sum = h2, sq = h2*h2;
        #pragma unroll
        for (int off = 1; off < 64; off <<= 1){
            sum += __shfl_xor(sum, off);
            sq  += __shfl_xor(sq,  off);
        }
        const int wv = (threadIdx.x >> 6) & 1;
        if ((threadIdx.x & 63) == 0){ redA[g][wv] = sum; scr[g][wv] = sq; }
    }
    __syncthreads();
    {
        const float tsum = redA[g][0] + redA[g][1];
        const float tsq  = scr[g][0] + scr[g][1];
        const float mu = tsum*(1.f/HID);
        const float var = tsq*(1.f/HID) - mu*mu;
        const float inv = rsqrtf(var + 1e-5f);
        z3s[g][h] = (h2 - mu)*inv*ln3g[h] + ln3b[h];
    }
    __syncthreads();

    float hid0 = bm1[h], hid1 = bm1[h+HID];
    for (int c = 0; c < HID; ++c){
        const float z = z3s[g][c];
        hid0 += z * w1[c*2*HID + h];
        hid1 += z * w1[c*2*HID + h + HID];
    }
    hls[g][h] = fmaxf(hid0, 0.f); hls[g][h+HID] = fmaxf(hid1, 0.f);
    __syncthreads();
    float outv = bm2[h] + h2;
    for (int j = 0; j < 2*HID; ++j) outv += hls[g][j]*w2[j*HID + h];
    Hn[(size_t)(b*NN + s)*HID + h] = outv;
}

// ---------------------------------------------------------------------------
// GAT (unchanged)
// ---------------------------------------------------------------------------
__device__ __forceinline__ void edge_decode(const int* __restrict__ ei, int e,
                                            int& src, int& dst, bool& dropped)
{
    if (e < NEDGEB){
        const int bb = e >> 15, k = e & (NEDGE-1);
        const int s0 = ei[k], d0 = ei[NEDGE + k];
        src = s0 + bb*NN; dst = d0 + bb*NN;
        dropped = (s0 == d0);
    } else { src = dst = e - NEDGEB; dropped = false; }
}

__global__ void k_gat1_lin(const float* __restrict__ Hn, const float* __restrict__ W,
                           const float* __restrict__ asrc, const float* __restrict__ adst,
                           bf16* __restrict__ hw, float* __restrict__ als, float* __restrict__ ald)
{
    const int nid = blockIdx.x, c = threadIdx.x;   // 128
    __shared__ float hr[HID], r1[HID], r2[HID];
    hr[c] = Hn[(size_t)nid*HID + c];
    __syncthreads();
    float a = 0.f;
    for (int k = 0; k < HID; ++k) a += hr[k]*W[k*HID + c];
    hw[(size_t)nid*HID + c] = f2b(a);
    r1[c] = a*asrc[c]; r2[c] = a*adst[c];
    __syncthreads();
    for (int st = 16; st > 0; st >>= 1){
        if ((c & 31) < st){ r1[c] += r1[c+st]; r2[c] += r2[c+st]; }
        __syncthreads();
    }
    if ((c & 31) == 0){
        als[nid*NHEADS + (c>>5)] = r1[c];
        ald[nid*NHEADS + (c>>5)] = r2[c];
    }
}

__global__ void k_gat_edge1(const int* __restrict__ ei, const float* __restrict__ als,
                            const float* __restrict__ ald, bf16* __restrict__ ex,
                            float* __restrict__ denom)
{
    const int idx = blockIdx.x*blockDim.x + threadIdx.x;
    if (idx >= NETOT*NHEADS) return;
    const int e = idx >> 2, hd = idx & 3;
    int src, dst; bool drop;
    edge_decode(ei, e, src, dst, drop);
    if (drop){ ex[idx] = f2b(0.f); return; }
    float a = als[src*NHEADS + hd] + ald[dst*NHEADS + hd];
    a = a > 0.f ? a : 0.2f*a;
    const bf16 vb = f2b(__expf(a));
    ex[idx] = vb;
    atomicAdd(&denom[dst*NHEADS + hd], b2f(vb));
}

__global__ void k_gat_agg1(const int* __restrict__ ei, const bf16* __restrict__ ex,
                           const float* __restrict__ denom, const bf16* __restrict__ hw,
                           float* __restrict__ agg)
{
    const int t = blockIdx.x*blockDim.x + threadIdx.x;   // NETOT*128
    const int e = t >> 7, c = t & 127;
    if (e >= NETOT) return;
    const float x = b2f(ex[e*NHEADS + (c>>5)]);
    if (x == 0.f) return;
    int src, dst; bool drop;
    edge_decode(ei, e, src, dst, drop);
    const float w = x / denom[dst*NHEADS + (c>>5)];
    atomicAdd(&agg[(size_t)dst*HID + c], w * b2f(hw[(size_t)src*HID + c]));
}

__global__ void k_gat1_fin(const float* __restrict__ agg, const float* __restrict__ bias,
                           bf16* __restrict__ g1)
{
    const int t = blockIdx.x*blockDim.x + threadIdx.x;
    if (t >= NNODE*HID) return;
    const float v = agg[t] + bias[t & 127];
    g1[t] = f2b(v > 0.f ? v : expm1f(v));    // elu
}

__global__ void k_gat2_lin(const bf16* __restrict__ g1, const float* __restrict__ W,
                           const float* __restrict__ asrc, const float* __restrict__ adst,
                           bf16* __restrict__ hw2, float* __restrict__ al2s, float* __restrict__ al2d)
{
    const int nid = blockIdx.x, c = threadIdx.x;    // 64 threads = 1 wave
    __shared__ float hr[HID];
    hr[c] = b2f(g1[(size_t)nid*HID + c]);
    hr[c+64] = b2f(g1[(size_t)nid*HID + c + 64]);
    __syncthreads();
    float a = 0.f;
    for (int k = 0; k < HID; ++k) a += hr[k]*W[k*OUTCH + c];
    hw2[(size_t)nid*OUTCH + c] = f2b(a);
    float s1 = a*asrc[c], s2 = a*adst[c];
    #pragma unroll
    for (int off = 32; off > 0; off >>= 1){
        s1 += __shfl_down(s1, off);
        s2 += __shfl_down(s2, off);
    }
    if (c == 0){ al2s[nid] = s1; al2d[nid] = s2; }
}

__global__ void k_gat_edge2(const int* __restrict__ ei, const float* __restrict__ als,
                            const float* __restrict__ ald, bf16* __restrict__ ex,
                            float* __restrict__ denom)
{
    const int e = blockIdx.x*blockDim.x + threadIdx.x;
    if (e >= NETOT) return;
    int src, dst; bool drop;
    edge_decode(ei, e, src, dst, drop);
    if (drop){ ex[e] = f2b(0.f); return; }
    float a = als[src] + ald[dst];
    a = a > 0.f ? a : 0.2f*a;
    const bf16 vb = f2b(__expf(a));
    ex[e] = vb;
    atomicAdd(&denom[dst], b2f(vb));
}

__global__ void k_gat_agg2(const int* __restrict__ ei, const bf16* __restrict__ ex,
                           const float* __restrict__ denom, const bf16* __restrict__ hw2,
                           float* __restrict__ agg)
{
    const int t = blockIdx.x*blockDim.x + threadIdx.x;   // NETOT*64
    const int e = t >> 6, c = t & 63;
    if (e >= NETOT) return;
    const float x = b2f(ex[e]);
    if (x == 0.f) return;
    int src, dst; bool drop;
    edge_decode(ei, e, src, dst, drop);
    const float w = x / denom[dst];
    atomicAdd(&agg[(size_t)dst*OUTCH + c], w * b2f(hw2[(size_t)src*OUTCH + c]));
}

__global__ void k_final(const float* __restrict__ agg2, const float* __restrict__ g2b,
                        const float* __restrict__ fw, const float* __restrict__ fb,
                        float* __restrict__ out)
{
    const int nid = blockIdx.x, c = threadIdx.x;    // 64
    __shared__ float g[OUTCH];
    g[c] = agg2[(size_t)nid*OUTCH + c] + g2b[c];
    __syncthreads();
    if (c < OUTF){
        float o = fb[c];
        for (int k = 0; k < OUTCH; ++k) o += g[k]*fw[k*OUTF + c];
        const int b = nid >> 11, n = nid & (NN-1);
        out[((size_t)b*OUTF + c)*NN + n] = o;
    }
}

// ---------------------------------------------------------------------------
extern "C" void kernel_launch(void* const* d_in, const int* in_sizes, int n_in,
                              void* d_out, int out_size, void* d_ws, size_t ws_size,
                              hipStream_t stream)
{
    const float* x    = (const float*)d_in[0];
    const int*  ei    = (const int*)d_in[1];
    const float* ln1g = (const float*)d_in[2];  const float* ln1b = (const float*)d_in[3];
    const float* t_wq = (const float*)d_in[4];  const float* t_bq = (const float*)d_in[5];
    const float* t_wk = (const float*)d_in[6];  const float* t_bk = (const float*)d_in[7];
    const float* t_wv = (const float*)d_in[8];  const float* t_bv = (const float*)d_in[9];
    const float* t_wo = (const float*)d_in[10]; const float* t_bo = (const float*)d_in[11];
    const float* skw  = (const float*)d_in[12]; const float* skb  = (const float*)d_in[13];
    const float* ln2g = (const float*)d_in[14]; const float* ln2b = (const float*)d_in[15];
    const float* s_wq = (const float*)d_in[16]; const float* s_bq = (const float*)d_in[17];
    const float* s_wk = (const float*)d_in[18]; const float* s_bk = (const float*)d_in[19];
    const float* s_wv = (const float*)d_in[20]; const float* s_bv = (const float*)d_in[21];
    const float* s_wo = (const float*)d_in[22]; const float* s_bo = (const float*)d_in[23];
    const float* ln3g = (const float*)d_in[24]; const float* ln3b = (const float*)d_in[25];
    const float* w1   = (const float*)d_in[26]; const float* b1   = (const float*)d_in[27];
    const float* w2   = (const float*)d_in[28]; const float* b2   = (const float*)d_in[29];
    const float* g1w  = (const float*)d_in[30];
    const float* g1as = (const float*)d_in[31]; const float* g1ad = (const float*)d_in[32];
    const float* g1b  = (const float*)d_in[33];
    const float* g2w  = (const float*)d_in[34];
    const float* g2as = (const float*)d_in[35]; const float* g2ad = (const float*)d_in[36];
    const float* g2b  = (const float*)d_in[37];
    const float* ffw  = (const float*)d_in[38]; const float* ffb  = (const float*)d_in[39];
    float* out = (float*)d_out;

    const size_t MiB = 1024u*1024u;
    const bool wide = ws_size >= 52*MiB;   // K(16)+Vt(16)+CXH1(16)+Hn(4)

    char* base = (char*)d_ws;
    bf16 *Kb, *Vtb, *CXH1;
    float* Hn;
    char* gat_base;
    char* mbase;
    if (wide){
        Kb   = (bf16*)(base + 0*MiB);      // 16 MiB
        Vtb  = (bf16*)(base + 16*MiB);     // 16 MiB
        CXH1 = (bf16*)(base + 32*MiB);     // 16 MiB
        Hn   = (float*)(base + 48*MiB);    // 4 MiB
        gat_base = base;                   // aliases Kb/Vtb (dead after k_h1)
        mbase = base + 13*MiB;             // inside dead Kb, past GAT scratch
    } else {
        CXH1 = (bf16*)(base + 0*MiB);      // 16 MiB
        Hn   = (float*)(base + 16*MiB);    // 4 MiB
        Kb   = (bf16*)(base + 20*MiB);     // 0.5 MiB (one slice)
        Vtb  = (bf16*)(base + 20*MiB + 512u*1024u);
        gat_base = base;                   // aliases CXH1 (dead after k_mix)
        mbase = base + 20*MiB;             // dead Kb region after attn
    }
    float* Mw  = (float*)mbase;                         // 64 KB
    float* vkw = (float*)(mbase + 64*1024);             // 512 B
    float* vqw = (float*)(mbase + 64*1024 + 512);       // 512 B
    float* sbb = (float*)(mbase + 64*1024 + 1024);      // 4 B

    // GAT scratch (~12.9 MiB) inside gat_base
    char* w = gat_base;
    auto alloc = [&](size_t bytes){ void* p = (void*)w; w += (bytes + 255) & ~(size_t)255; return p; };
    bf16*  hw1  = (bf16*) alloc((size_t)NNODE*HID*sizeof(bf16));
    float* als1 = (float*)alloc((size_t)NNODE*NHEADS*sizeof(float));
    float* ald1 = (float*)alloc((size_t)NNODE*NHEADS*sizeof(float));
    bf16*  ex1  = (bf16*) alloc((size_t)NETOT*NHEADS*sizeof(bf16));
    float* den1 = (float*)alloc((size_t)NNODE*NHEADS*sizeof(float));
    float* agg1 = (float*)alloc((size_t)NNODE*HID*sizeof(float));
    bf16*  g1o  = (bf16*) alloc((size_t)NNODE*HID*sizeof(bf16));
    bf16*  hw2  = (bf16*) alloc((size_t)NNODE*OUTCH*sizeof(bf16));
    float* als2 = (float*)alloc((size_t)NNODE*sizeof(float));
    float* ald2 = (float*)alloc((size_t)NNODE*sizeof(float));
    bf16*  ex2  = (bf16*) alloc((size_t)NETOT*sizeof(bf16));
    float* den2 = (float*)alloc((size_t)NNODE*sizeof(float));
    float* agg2 = (float*)alloc((size_t)NNODE*OUTCH*sizeof(float));

    // ---- trunk ----
    if (wide){
        k_kv<<<PROWS, HID, 0, stream>>>(x, ln1g, ln1b, t_wk, t_bk, t_wv, t_bv, 0, Kb, Vtb);
        k_attn_mfma<<<dim3(BM, NTILE), 256, 0, stream>>>(x, Kb, Vtb, ln1g, ln1b,
                                                         t_wq, t_bq, 0, CXH1);
        k_h1<<<dim3(BM, NTILE), 256, 0, stream>>>(x, t_wo, skw, t_bo, skb, 0, CXH1);
    } else {
        for (int s = 0; s < BM; ++s){
            k_kv<<<NN, HID, 0, stream>>>(x, ln1g, ln1b, t_wk, t_bk, t_wv, t_bv, s*NN, Kb, Vtb);
            k_attn_mfma<<<dim3(1, NTILE), 256, 0, stream>>>(x, Kb, Vtb, ln1g, ln1b,
                                                            t_wq, t_bq, s, CXH1);
        }
        k_h1<<<dim3(BM, NTILE), 256, 0, stream>>>(x, t_wo, skw, t_bo, skb, 0, CXH1);
    }
    // node-attn precompute (Kb region dead now)
    k_prep<<<16, 256, 0, stream>>>(s_wq, s_wk, Mw);
    k_prep2<<<1, 128, 0, stream>>>(s_wq, s_wk, s_bq, s_bk, vkw, vqw, sbb);

    k_mix<<<NNODE/4, 512, 0, stream>>>(CXH1, ln2g, ln2b, Mw, vkw, vqw, sbb,
                                       s_bv, s_wv, s_wo, s_bo, ln3g, ln3b,
                                       w1, b1, w2, b2, Hn);

    // ---- GAT ----
    hipMemsetAsync(den1, 0, (size_t)NNODE*NHEADS*sizeof(float), stream);
    hipMemsetAsync(agg1, 0, (size_t)NNODE*HID*sizeof(float), stream);
    hipMemsetAsync(den2, 0, (size_t)NNODE*sizeof(float), stream);
    hipMemsetAsync(agg2, 0, (size_t)NNODE*OUTCH*sizeof(float), stream);

    k_gat1_lin<<<NNODE, HID, 0, stream>>>(Hn, g1w, g1as, g1ad, hw1, als1, ald1);
    k_gat_edge1<<<(NETOT*NHEADS + 255)/256, 256, 0, stream>>>(ei, als1, ald1, ex1, den1);
    k_gat_agg1<<<(NETOT*HID)/256, 256, 0, stream>>>(ei, ex1, den1, hw1, agg1);
    k_gat1_fin<<<(NNODE*HID)/256, 256, 0, stream>>>(agg1, g1b, g1o);
    k_gat2_lin<<<NNODE, OUTCH, 0, stream>>>(g1o, g2w, g2as, g2ad, hw2, als2, ald2);
    k_gat_edge2<<<(NETOT + 255)/256, 256, 0, stream>>>(ei, als2, ald2, ex2, den2);
    k_gat_agg2<<<(NETOT*OUTCH)/256, 256, 0, stream>>>(ei, ex2, den2, hw2, agg2);
    k_final<<<NNODE, OUTCH, 0, stream>>>(agg2, g2b, ffw, ffb, out);
}

// Round 17
// 618.727 us; speedup vs baseline: 1.0205x; 1.0205x over previous
//
#include <hip/hip_runtime.h>
#include <hip/hip_bf16.h>
#include <stdint.h>

// ---------------------------------------------------------------------------
// PFGAT. R17: pipeline fusion 18 -> 9 dispatches.
//  - gat1_lin fused into k_mix (Hn buffer + roundtrip deleted)
//  - GAT edge-softmax fused into agg kernels (unnormalized accumulate,
//    divide at consumption; ex buffers deleted; fp32 ex, more accurate)
//  - fin1 fused into gat2_lin; fin2 (divide) into k_final
//  - k_prep + k_prep2 + 4 memsets merged into one kernel
// Hot kernels (k_kv / attn / k_h1) unchanged from R16.
// ---------------------------------------------------------------------------

#define BB     4
#define TT     8
#define NN     2048
#define FIN    16
#define HID    128
#define BM     (BB*TT)            // 32 attention slices
#define PROWS  (BM*NN)            // 65536 rows
#define NHEADS 4
#define OUTCH  64
#define OUTF   14
#define NEDGE  32768
#define NEDGEB (NEDGE*BB)         // 131072
#define NNODE  (BB*NN)            // 8192
#define NETOT  (NEDGEB + NNODE)   // 139264 (edges + self loops)

#define TQ     64                 // query tile (rows per block)
#define NTILE  (NN/TQ)            // 32 query tiles per slice

typedef __hip_bfloat16 bf16;
typedef __attribute__((ext_vector_type(8))) short bf16x8;   // MFMA A/B frag
typedef __attribute__((ext_vector_type(4))) float f32x4;    // MFMA C/D frag

__device__ __forceinline__ float b2f(bf16 v){ return __bfloat162float(v); }
__device__ __forceinline__ bf16  f2b(float f){ return __float2bfloat16(f); }

// ---------------------------------------------------------------------------
// K1: per row: LN1 over F=16 -> k,v projections; K row-major, V key-tiled.
// ---------------------------------------------------------------------------
__global__ void k_kv(const float* __restrict__ x,
                     const float* __restrict__ g1, const float* __restrict__ bb1,
                     const float* __restrict__ wk, const float* __restrict__ bk,
                     const float* __restrict__ wv, const float* __restrict__ bv,
                     int in_off, bf16* __restrict__ K, bf16* __restrict__ Vt)
{
    const int rloc = blockIdx.x;
    const int rin  = rloc + in_off;
    const int h = threadIdx.x;       // 0..127
    __shared__ float xr[FIN], lnv[FIN];
    if (h < FIN) xr[h] = x[(size_t)rin*FIN + h];
    __syncthreads();
    float mu = 0.f;
    #pragma unroll
    for (int f = 0; f < FIN; ++f) mu += xr[f];
    mu *= (1.f/FIN);
    float var = 0.f;
    #pragma unroll
    for (int f = 0; f < FIN; ++f){ float d = xr[f]-mu; var += d*d; }
    var *= (1.f/FIN);
    const float inv = rsqrtf(var + 1e-5f);
    if (h < FIN) lnv[h] = (xr[h]-mu)*inv*g1[h] + bb1[h];
    __syncthreads();
    float ak = bk[h], av = bv[h];
    #pragma unroll
    for (int f = 0; f < FIN; ++f){
        const float l = lnv[f];
        ak += l * wk[f*HID + h];
        av += l * wv[f*HID + h];
    }
    K[(size_t)rloc*HID + h] = f2b(ak);
    const int slice = rloc >> 11;            // 0 in narrow mode
    const int key   = rloc & (NN-1);
    Vt[(((size_t)slice*(NN/32) + (key>>5))*HID + h)*32 + (key&31)] = f2b(av);
}

// ---------------------------------------------------------------------------
// K2 (MFMA flash): unchanged.
// ---------------------------------------------------------------------------
__global__ __launch_bounds__(256)
void k_attn_mfma(const float* __restrict__ x,
                 const bf16* __restrict__ K, const bf16* __restrict__ Vt,
                 const float* __restrict__ g1, const float* __restrict__ bb1,
                 const float* __restrict__ wq, const float* __restrict__ bq,
                 int slice_off, bf16* __restrict__ CX)
{
    const int tile  = (NTILE-1) - (int)blockIdx.y;   // big tiles first
    const int q0    = tile*TQ;
    const int slice = blockIdx.x + slice_off;
    const int t     = threadIdx.x;
    const int w     = t >> 6;
    const int lane  = t & 63;
    const int quad  = lane >> 4;
    const int l16   = lane & 15;
    const int wr0   = w*16;

    __shared__ float xs [TQ][FIN];
    __shared__ bf16  Qs [TQ][136];
    __shared__ bf16  Ps [4][16][40];
    __shared__ bf16  Ks [32*136];
    __shared__ bf16  Vs [128*40];

    for (int u = t; u < TQ*FIN; u += 256)
        ((float*)xs)[u] = x[((size_t)slice*NN + q0)*FIN + u];
    __syncthreads();
    if (t < TQ){
        float mu = 0.f;
        #pragma unroll
        for (int f = 0; f < FIN; ++f) mu += xs[t][f];
        mu *= (1.f/FIN);
        float var = 0.f;
        #pragma unroll
        for (int f = 0; f < FIN; ++f){ float d = xs[t][f]-mu; var += d*d; }
        var *= (1.f/FIN);
        const float inv = rsqrtf(var + 1e-5f);
        #pragma unroll
        for (int f = 0; f < FIN; ++f)
            xs[t][f] = (xs[t][f]-mu)*inv*g1[f] + bb1[f];
    }
    __syncthreads();
    {
        const int ch = t & 127, half = t >> 7;
        const float scale = 0.08838834764831845f;
        float wqr[FIN];
        #pragma unroll
        for (int f = 0; f < FIN; ++f) wqr[f] = wq[f*HID + ch];
        const float bqv = bq[ch];
        for (int j = 0; j < 32; ++j){
            const int row = half*32 + j;
            const float4 l0 = ((const float4*)&xs[row][0])[0];
            const float4 l1 = ((const float4*)&xs[row][0])[1];
            const float4 l2 = ((const float4*)&xs[row][0])[2];
            const float4 l3 = ((const float4*)&xs[row][0])[3];
            float a = bqv;
            a += l0.x*wqr[0]  + l0.y*wqr[1]  + l0.z*wqr[2]  + l0.w*wqr[3];
            a += l1.x*wqr[4]  + l1.y*wqr[5]  + l1.z*wqr[6]  + l1.w*wqr[7];
            a += l2.x*wqr[8]  + l2.y*wqr[9]  + l2.z*wqr[10] + l2.w*wqr[11];
            a += l3.x*wqr[12] + l3.y*wqr[13] + l3.z*wqr[14] + l3.w*wqr[15];
            Qs[row][ch] = f2b(a*scale);
        }
    }
    __syncthreads();

    bf16x8 qf[4];
    #pragma unroll
    for (int ks = 0; ks < 4; ++ks)
        qf[ks] = *(const bf16x8*)(const void*)&Qs[wr0 + l16][ks*32 + quad*8];

    f32x4 O[8];
    #pragma unroll
    for (int ct = 0; ct < 8; ++ct) O[ct] = (f32x4){0.f,0.f,0.f,0.f};
    float l_[4] = {0.f,0.f,0.f,0.f};

    const size_t kb = (size_t)blockIdx.x * NN * HID;
    const size_t vb = (size_t)blockIdx.x * (size_t)(NN/32) * HID*32;
    const int jend_blk = q0 + TQ - 1;
    const int my_jmax  = q0 + wr0 + 15;
    const int brow = q0 + wr0 + quad*4;

    for (int j0 = 0; j0 <= jend_blk; j0 += 32){
        {
            const bf16* ksl = K  + kb + (size_t)j0*HID;
            const bf16* vsl = Vt + vb + (size_t)(j0>>5)*(HID*32);
            #pragma unroll
            for (int it = 0; it < 2; ++it){
                const int c = t + it*256;
                *(bf16x8*)(void*)&Ks[(c>>4)*136 + (c&15)*8] =
                    *(const bf16x8*)(const void*)(ksl + c*8);
                *(bf16x8*)(void*)&Vs[(c>>2)*40 + (c&3)*8] =
                    *(const bf16x8*)(const void*)(vsl + c*8);
            }
        }
        __syncthreads();

        if (j0 <= my_jmax){
            f32x4 S0 = (f32x4){0.f,0.f,0.f,0.f}, S1 = S0;
            #pragma unroll
            for (int ks = 0; ks < 4; ++ks){
                const bf16x8 kf0 = *(const bf16x8*)(const void*)
                    &Ks[(l16     )*136 + ks*32 + quad*8];
                const bf16x8 kf1 = *(const bf16x8*)(const void*)
                    &Ks[(l16 + 16)*136 + ks*32 + quad*8];
                S0 = __builtin_amdgcn_mfma_f32_16x16x32_bf16(qf[ks], kf0, S0, 0, 0, 0);
                S1 = __builtin_amdgcn_mfma_f32_16x16x32_bf16(qf[ks], kf1, S1, 0, 0, 0);
            }
            const int c0j = j0 + l16, c1j = c0j + 16;
            #pragma unroll
            for (int r = 0; r < 4; ++r){
                const float s0 = (c0j <= brow + r) ? S0[r] : -1e30f;
                const float s1 = (c1j <= brow + r) ? S1[r] : -1e30f;
                const bf16 hb0 = f2b(__expf(s0));
                const bf16 hb1 = f2b(__expf(s1));
                Ps[w][quad*4 + r][l16]      = hb0;
                Ps[w][quad*4 + r][l16 + 16] = hb1;
                l_[r] += b2f(hb0) + b2f(hb1);
            }
            const bf16x8 pf = *(const bf16x8*)(const void*)&Ps[w][l16][quad*8];
            #pragma unroll
            for (int ct = 0; ct < 8; ++ct){
                const bf16x8 vf = *(const bf16x8*)(const void*)
                    &Vs[(ct*16 + l16)*40 + quad*8];
                O[ct] = __builtin_amdgcn_mfma_f32_16x16x32_bf16(pf, vf, O[ct], 0, 0, 0);
            }
        }
        __syncthreads();
    }

    {
        float inv[4];
        #pragma unroll
        for (int r = 0; r < 4; ++r){
            float rs = l_[r];
            rs += __shfl_xor(rs, 1);
            rs += __shfl_xor(rs, 2);
            rs += __shfl_xor(rs, 4);
            rs += __shfl_xor(rs, 8);
            inv[r] = 1.f/rs;
        }
        #pragma unroll
        for (int ct = 0; ct < 8; ++ct)
        #pragma unroll
        for (int r = 0; r < 4; ++r)
            Qs[wr0 + quad*4 + r][ct*16 + l16] = f2b(O[ct][r]*inv[r]);
    }
    __syncthreads();
    {
        const int row = t >> 2, ch0 = (t & 3)*32;
        bf16* dst = CX + ((size_t)slice*NN + q0 + row)*HID + ch0;
        #pragma unroll
        for (int c = 0; c < 4; ++c)
            *(bf16x8*)(void*)(dst + c*8) =
                *(const bf16x8*)(const void*)&Qs[row][ch0 + c*8];
    }
}

// ---------------------------------------------------------------------------
// K_H1 (MFMA epilogue GEMM): unchanged.
// ---------------------------------------------------------------------------
__global__ __launch_bounds__(256)
void k_h1(const float* __restrict__ x,
          const float* __restrict__ t_wo, const float* __restrict__ skw,
          const float* __restrict__ t_bo, const float* __restrict__ skb,
          int slice_off, bf16* __restrict__ CXH1)
{
    const int slice = blockIdx.x + slice_off;
    const int q0    = blockIdx.y * TQ;
    const int t     = threadIdx.x;
    const int w     = t >> 6;
    const int lane  = t & 63;
    const int quad  = lane >> 4;
    const int l16   = lane & 15;
    const int wr0   = w*16;

    __shared__ bf16 Aext[TQ][168];
    __shared__ bf16 Bext[HID][168];

    {
        const bf16* src = CXH1 + ((size_t)slice*NN + q0)*HID;
        #pragma unroll
        for (int it = 0; it < 4; ++it){
            const int c = t + it*256;
            *(bf16x8*)(void*)&Aext[c>>4][(c&15)*8] =
                *(const bf16x8*)(const void*)(src + c*8);
        }
    }
    #pragma unroll
    for (int it = 0; it < 4; ++it){
        const int u = t + it*256;
        const int row = u >> 4, f = u & 15;
        Aext[row][128 + f] = f2b(x[((size_t)slice*NN + q0 + row)*FIN + f]);
    }
    #pragma unroll
    for (int it = 0; it < 4; ++it){
        const int u = t + it*256;
        Aext[u>>4][144 + (u&15)] = f2b(0.f);
    }
    #pragma unroll
    for (int it = 0; it < 16; ++it){
        const int idx = t + it*256;
        const int c = idx >> 5, ch4 = (idx & 31)*4;
        const float4 v = ((const float4*)t_wo)[idx];
        Bext[ch4+0][c] = f2b(v.x);
        Bext[ch4+1][c] = f2b(v.y);
        Bext[ch4+2][c] = f2b(v.z);
        Bext[ch4+3][c] = f2b(v.w);
    }
    #pragma unroll
    for (int it = 0; it < 2; ++it){
        const int idx = t + it*256;
        const int f = idx >> 5, ch4 = (idx & 31)*4;
        const float4 v = ((const float4*)skw)[idx];
        Bext[ch4+0][128+f] = f2b(v.x);
        Bext[ch4+1][128+f] = f2b(v.y);
        Bext[ch4+2][128+f] = f2b(v.z);
        Bext[ch4+3][128+f] = f2b(v.w);
    }
    #pragma unroll
    for (int it = 0; it < 8; ++it){
        const int u = t + it*256;
        Bext[u>>4][144 + (u&15)] = f2b(0.f);
    }
    __syncthreads();

    f32x4 O[8];
    #pragma unroll
    for (int ct = 0; ct < 8; ++ct) O[ct] = (f32x4){0.f,0.f,0.f,0.f};
    #pragma unroll
    for (int ks = 0; ks < 5; ++ks){
        const bf16x8 af = *(const bf16x8*)(const void*)&Aext[wr0 + l16][ks*32 + quad*8];
        #pragma unroll
        for (int ct = 0; ct < 8; ++ct){
            const bf16x8 bf = *(const bf16x8*)(const void*)&Bext[ct*16 + l16][ks*32 + quad*8];
            O[ct] = __builtin_amdgcn_mfma_f32_16x16x32_bf16(af, bf, O[ct], 0, 0, 0);
        }
    }
    #pragma unroll
    for (int ct = 0; ct < 8; ++ct){
        const int col = ct*16 + l16;
        const float bias = t_bo[col] + skb[col];
        #pragma unroll
        for (int r = 0; r < 4; ++r)
            Aext[wr0 + quad*4 + r][col] = f2b(O[ct][r] + bias);
    }
    __syncthreads();
    {
        const int row = t >> 2, ch0 = (t & 3)*32;
        bf16* dst = CXH1 + ((size_t)slice*NN + q0 + row)*HID + ch0;
        #pragma unroll
        for (int c = 0; c < 4; ++c)
            *(bf16x8*)(void*)(dst + c*8) =
                *(const bf16x8*)(const void*)&Aext[row][ch0 + c*8];
    }
}

// ---------------------------------------------------------------------------
// K_PREP (merged): blocks 0-15 compute M = s_wq@s_wk^T; block 16 computes
// vk/vq/sbb; ALL 32 blocks zero the GAT accumulator region.
// ---------------------------------------------------------------------------
__global__ __launch_bounds__(256)
void k_prep(const float* __restrict__ s_wq, const float* __restrict__ s_wk,
            const float* __restrict__ bq, const float* __restrict__ bk,
            float* __restrict__ M, float* __restrict__ vk,
            float* __restrict__ vq, float* __restrict__ sbb,
            float* __restrict__ zp, int zn)
{
    const int b = blockIdx.x;          // 0..31
    const int t = threadIdx.x;
    for (int u = b*256 + t; u < zn; u += 32*256) zp[u] = 0.f;
    __shared__ float wk_s[HID*HID];
    __shared__ float wq_s[8][HID];
    if (b < 16){
        for (int u = t; u < HID*HID; u += 256) wk_s[u] = s_wk[u];
        for (int u = t; u < 8*HID;   u += 256) ((float*)wq_s)[u] = s_wq[b*8*HID + u];
        __syncthreads();
        #pragma unroll
        for (int i = 0; i < 4; ++i){
            const int e = t + i*256;
            const int a = e >> 7, c = e & 127;
            float acc = 0.f;
            for (int hh = 0; hh < HID; ++hh) acc += wq_s[a][hh]*wk_s[c*HID + hh];
            M[(size_t)(b*8 + a)*HID + c] = acc;
        }
    } else if (b == 16 && t < HID){
        float a1 = 0.f, a2 = 0.f;
        for (int hh = 0; hh < HID; ++hh){
            a1 += bq[hh]*s_wk[t*HID + hh];
            a2 += s_wq[t*HID + hh]*bk[hh];
        }
        vk[t] = a1; vq[t] = a2;
        if (t == 0){
            float s = 0.f;
            for (int hh = 0; hh < HID; ++hh) s += bq[hh]*bk[hh];
            *sbb = s;
        }
    }
}

// ---------------------------------------------------------------------------
// K3 (R17): bilinear node attention + fused GAT1 linear. 4 nodes/block.
// Emits hw1 (bf16), als1, ald1 directly (no Hn buffer).
// ---------------------------------------------------------------------------
__global__ __launch_bounds__(512)
void k_mix(const bf16* __restrict__ H1,
           const float* __restrict__ ln2g, const float* __restrict__ ln2b,
           const float* __restrict__ M, const float* __restrict__ vk,
           const float* __restrict__ vq, const float* __restrict__ sbbp,
           const float* __restrict__ s_bv, const float* __restrict__ s_wv,
           const float* __restrict__ s_wo, const float* __restrict__ s_bo,
           const float* __restrict__ ln3g, const float* __restrict__ ln3b,
           const float* __restrict__ w1, const float* __restrict__ bm1,
           const float* __restrict__ w2, const float* __restrict__ bm2,
           const float* __restrict__ g1w, const float* __restrict__ g1as,
           const float* __restrict__ g1ad,
           bf16* __restrict__ hw1, float* __restrict__ als1, float* __restrict__ ald1)
{
    const int g  = threadIdx.x >> 7;          // node slot 0..3
    const int h  = threadIdx.x & 127;
    const int blk = blockIdx.x*4 + g;         // b*NN + s
    const int b = blk >> 11, s = blk & (NN-1);

    __shared__ float h1[4][TT][HID], z2[4][TT][HID];
    __shared__ float rp[4][HID], zb[4][HID], cx2[4][HID], z3s[4][HID];
    __shared__ float hls[4][2*HID];
    __shared__ float scr[4][TT];
    __shared__ float mu_s[4][TT], inv_s[4][TT];
    __shared__ float redA[4][2];

    #pragma unroll
    for (int m = 0; m < TT; ++m)
        h1[g][m][h] = b2f(H1[((size_t)(b*TT + m)*NN + s)*HID + h]);
    __syncthreads();

    // ---- LN2 stats: all 8 m in parallel ----
    {
        const int m = h >> 4, l16 = h & 15;
        float sum = 0.f, sq = 0.f;
        #pragma unroll
        for (int j = 0; j < 8; ++j){
            const float v = h1[g][m][l16 + 16*j];
            sum += v; sq += v*v;
        }
        sum += __shfl_xor(sum, 1); sq += __shfl_xor(sq, 1);
        sum += __shfl_xor(sum, 2); sq += __shfl_xor(sq, 2);
        sum += __shfl_xor(sum, 4); sq += __shfl_xor(sq, 4);
        sum += __shfl_xor(sum, 8); sq += __shfl_xor(sq, 8);
        if (l16 == 0){
            const float mu = sum*(1.f/HID);
            const float var = sq*(1.f/HID) - mu*mu;
            mu_s[g][m] = mu;
            inv_s[g][m] = rsqrtf(var + 1e-5f);
        }
    }
    __syncthreads();
    {
        const float g2v = ln2g[h], b2v = ln2b[h];
        #pragma unroll
        for (int m = 0; m < TT; ++m)
            z2[g][m][h] = (h1[g][m][h] - mu_s[g][m])*inv_s[g][m]*g2v + b2v;
    }
    __syncthreads();

    // ---- rp = z7@M + vk; sbq partial ----
    {
        float r = vk[h];
        for (int a = 0; a < HID; ++a) r += z2[g][TT-1][a]*M[a*HID + h];
        rp[g][h] = r;
        float p = vq[h]*z2[g][TT-1][h];
        #pragma unroll
        for (int off = 1; off < 64; off <<= 1) p += __shfl_xor(p, off);
        const int wv = (threadIdx.x >> 6) & 1;
        if ((threadIdx.x & 63) == 0) redA[g][wv] = p;
    }
    __syncthreads();

    // ---- scr[m] = rp.z2[m] + sbq + sbb ----
    {
        const int m = h >> 4, l16 = h & 15;
        float d = 0.f;
        #pragma unroll
        for (int j = 0; j < 8; ++j){
            const int c = l16 + 16*j;
            d += rp[g][c]*z2[g][m][c];
        }
        d += __shfl_xor(d, 1);
        d += __shfl_xor(d, 2);
        d += __shfl_xor(d, 4);
        d += __shfl_xor(d, 8);
        if (l16 == 0){
            const float sbq = redA[g][0] + redA[g][1];
            scr[g][m] = (d + sbq + *sbbp) * 0.08838834764831845f;
        }
    }
    __syncthreads();

    // ---- softmax over 8 slots + zbar ----
    {
        float mx = -1e30f;
        #pragma unroll
        for (int m = 0; m < TT; ++m) mx = fmaxf(mx, scr[g][m]);
        float p[TT], se = 0.f;
        #pragma unroll
        for (int m = 0; m < TT; ++m){ p[m] = __expf(scr[g][m]-mx); se += p[m]; }
        const float isum = 1.f/se;
        float zz = 0.f;
        #pragma unroll
        for (int m = 0; m < TT; ++m) zz += p[m]*z2[g][m][h];
        zb[g][h] = zz*isum;
    }
    __syncthreads();

    // ---- ctx2 = zbar@s_wv + bv ----
    {
        float a = s_bv[h];
        for (int c = 0; c < HID; ++c) a += zb[g][c]*s_wv[c*HID + h];
        cx2[g][h] = a;
    }
    __syncthreads();

    // ---- o = ctx2@s_wo + bo; h2; LN3 ----
    float o = s_bo[h];
    for (int c = 0; c < HID; ++c) o += cx2[g][c]*s_wo[c*HID + h];
    const float h2 = h1[g][TT-1][h] + o;

    {
        float sum = h2, sq = h2*h2;
        #pragma unroll
        for (int off = 1; off < 64; off <<= 1){
            sum += __shfl_xor(sum, off);
            sq  += __shfl_xor(sq,  off);
        }
        const int wv = (threadIdx.x >> 6) & 1;
        if ((threadIdx.x & 63) == 0){ redA[g][wv] = sum; scr[g][wv] = sq; }
    }
    __syncthreads();
    {
        const float tsum = redA[g][0] + redA[g][1];
        const float tsq  = scr[g][0] + scr[g][1];
        const float mu = tsum*(1.f/HID);
        const float var = tsq*(1.f/HID) - mu*mu;
        const float inv = rsqrtf(var + 1e-5f);
        z3s[g][h] = (h2 - mu)*inv*ln3g[h] + ln3b[h];
    }
    __syncthreads();

    float hid0 = bm1[h], hid1 = bm1[h+HID];
    for (int c = 0; c < HID; ++c){
        const float z = z3s[g][c];
        hid0 += z * w1[c*2*HID + h];
        hid1 += z * w1[c*2*HID + h + HID];
    }
    hls[g][h] = fmaxf(hid0, 0.f); hls[g][h+HID] = fmaxf(hid1, 0.f);
    __syncthreads();
    float outv = bm2[h] + h2;
    for (int j = 0; j < 2*HID; ++j) outv += hls[g][j]*w2[j*HID + h];

    // ---- fused GAT1 linear: hn -> hw1, als1, ald1 ----
    cx2[g][h] = outv;                 // reuse cx2 as hn staging
    __syncthreads();
    {
        float a = 0.f;
        for (int k = 0; k < HID; ++k) a += cx2[g][k]*g1w[k*HID + h];
        hw1[(size_t)blk*HID + h] = f2b(a);
        float r1 = a*g1as[h], r2 = a*g1ad[h];
        #pragma unroll
        for (int off = 1; off < 32; off <<= 1){
            r1 += __shfl_xor(r1, off);
            r2 += __shfl_xor(r2, off);
        }
        if ((h & 31) == 0){
            als1[blk*NHEADS + (h>>5)] = r1;
            ald1[blk*NHEADS + (h>>5)] = r2;
        }
    }
}

// ---------------------------------------------------------------------------
// GAT aggregation (edge softmax fused; unnormalized accumulate + denom)
// ---------------------------------------------------------------------------
__device__ __forceinline__ void edge_decode(const int* __restrict__ ei, int e,
                                            int& src, int& dst, bool& dropped)
{
    if (e < NEDGEB){
        const int bb = e >> 15, k = e & (NEDGE-1);
        const int s0 = ei[k], d0 = ei[NEDGE + k];
        src = s0 + bb*NN; dst = d0 + bb*NN;
        dropped = (s0 == d0);
    } else { src = dst = e - NEDGEB; dropped = false; }
}

__global__ void k_gat_agg1(const int* __restrict__ ei, const float* __restrict__ als,
                           const float* __restrict__ ald, const bf16* __restrict__ hw,
                           float* __restrict__ agg, float* __restrict__ den)
{
    const int t = blockIdx.x*blockDim.x + threadIdx.x;   // NETOT*128
    const int e = t >> 7, c = t & 127;
    if (e >= NETOT) return;
    int src, dst; bool drop;
    edge_decode(ei, e, src, dst, drop);
    if (drop) return;
    const int hd = c >> 5;
    float a = als[src*NHEADS + hd] + ald[dst*NHEADS + hd];
    a = a > 0.f ? a : 0.2f*a;
    const float ex = __expf(a);
    atomicAdd(&agg[(size_t)dst*HID + c], ex * b2f(hw[(size_t)src*HID + c]));
    if ((c & 31) == 0) atomicAdd(&den[dst*NHEADS + hd], ex);
}

// gat2 linear with fused fin1 (divide + bias + elu)
__global__ void k_gat2_lin(const float* __restrict__ agg1, const float* __restrict__ den1,
                           const float* __restrict__ g1b,
                           const float* __restrict__ W,
                           const float* __restrict__ asrc, const float* __restrict__ adst,
                           bf16* __restrict__ hw2, float* __restrict__ al2s, float* __restrict__ al2d)
{
    const int nid = blockIdx.x, c = threadIdx.x;    // 64 threads = 1 wave
    __shared__ float hr[HID];
    {
        const float v0 = agg1[(size_t)nid*HID + c]      / den1[nid*NHEADS + (c>>5)]      + g1b[c];
        const float v1 = agg1[(size_t)nid*HID + c + 64] / den1[nid*NHEADS + ((c+64)>>5)] + g1b[c+64];
        hr[c]    = v0 > 0.f ? v0 : expm1f(v0);
        hr[c+64] = v1 > 0.f ? v1 : expm1f(v1);
    }
    __syncthreads();
    float a = 0.f;
    for (int k = 0; k < HID; ++k) a += hr[k]*W[k*OUTCH + c];
    hw2[(size_t)nid*OUTCH + c] = f2b(a);
    float s1 = a*asrc[c], s2 = a*adst[c];
    #pragma unroll
    for (int off = 32; off > 0; off >>= 1){
        s1 += __shfl_down(s1, off);
        s2 += __shfl_down(s2, off);
    }
    if (c == 0){ al2s[nid] = s1; al2d[nid] = s2; }
}

__global__ void k_gat_agg2(const int* __restrict__ ei, const float* __restrict__ als,
                           const float* __restrict__ ald, const bf16* __restrict__ hw2,
                           float* __restrict__ agg, float* __restrict__ den)
{
    const int t = blockIdx.x*blockDim.x + threadIdx.x;   // NETOT*64
    const int e = t >> 6, c = t & 63;
    if (e >= NETOT) return;
    int src, dst; bool drop;
    edge_decode(ei, e, src, dst, drop);
    if (drop) return;
    float a = als[src] + ald[dst];
    a = a > 0.f ? a : 0.2f*a;
    const float ex = __expf(a);
    atomicAdd(&agg[(size_t)dst*OUTCH + c], ex * b2f(hw2[(size_t)src*OUTCH + c]));
    if (c == 0) atomicAdd(&den[dst], ex);
}

__global__ void k_final(const float* __restrict__ agg2, const float* __restrict__ den2,
                        const float* __restrict__ g2b,
                        const float* __restrict__ fw, const float* __restrict__ fb,
                        float* __restrict__ out)
{
    const int nid = blockIdx.x, c = threadIdx.x;    // 64
    __shared__ float g[OUTCH];
    g[c] = agg2[(size_t)nid*OUTCH + c]/den2[nid] + g2b[c];
    __syncthreads();
    if (c < OUTF){
        float o = fb[c];
        for (int k = 0; k < OUTCH; ++k) o += g[k]*fw[k*OUTF + c];
        const int b = nid >> 11, n = nid & (NN-1);
        out[((size_t)b*OUTF + c)*NN + n] = o;
    }
}

// ---------------------------------------------------------------------------
extern "C" void kernel_launch(void* const* d_in, const int* in_sizes, int n_in,
                              void* d_out, int out_size, void* d_ws, size_t ws_size,
                              hipStream_t stream)
{
    const float* x    = (const float*)d_in[0];
    const int*  ei    = (const int*)d_in[1];
    const float* ln1g = (const float*)d_in[2];  const float* ln1b = (const float*)d_in[3];
    const float* t_wq = (const float*)d_in[4];  const float* t_bq = (const float*)d_in[5];
    const float* t_wk = (const float*)d_in[6];  const float* t_bk = (const float*)d_in[7];
    const float* t_wv = (const float*)d_in[8];  const float* t_bv = (const float*)d_in[9];
    const float* t_wo = (const float*)d_in[10]; const float* t_bo = (const float*)d_in[11];
    const float* skw  = (const float*)d_in[12]; const float* skb  = (const float*)d_in[13];
    const float* ln2g = (const float*)d_in[14]; const float* ln2b = (const float*)d_in[15];
    const float* s_wq = (const float*)d_in[16]; const float* s_bq = (const float*)d_in[17];
    const float* s_wk = (const float*)d_in[18]; const float* s_bk = (const float*)d_in[19];
    const float* s_wv = (const float*)d_in[20]; const float* s_bv = (const float*)d_in[21];
    const float* s_wo = (const float*)d_in[22]; const float* s_bo = (const float*)d_in[23];
    const float* ln3g = (const float*)d_in[24]; const float* ln3b = (const float*)d_in[25];
    const float* w1   = (const float*)d_in[26]; const float* b1   = (const float*)d_in[27];
    const float* w2   = (const float*)d_in[28]; const float* b2   = (const float*)d_in[29];
    const float* g1w  = (const float*)d_in[30];
    const float* g1as = (const float*)d_in[31]; const float* g1ad = (const float*)d_in[32];
    const float* g1b  = (const float*)d_in[33];
    const float* g2w  = (const float*)d_in[34];
    const float* g2as = (const float*)d_in[35]; const float* g2ad = (const float*)d_in[36];
    const float* g2b  = (const float*)d_in[37];
    const float* ffw  = (const float*)d_in[38]; const float* ffb  = (const float*)d_in[39];
    float* out = (float*)d_out;

    const size_t MiB = 1024u*1024u;
    const bool wide = ws_size >= 48*MiB;

    char* base = (char*)d_ws;
    bf16 *Kb, *Vtb, *CXH1;
    char* gat_base;
    char* mbase;
    if (wide){
        Kb   = (bf16*)(base + 0*MiB);      // 16 MiB
        Vtb  = (bf16*)(base + 16*MiB);     // 16 MiB
        CXH1 = (bf16*)(base + 32*MiB);     // 16 MiB
        gat_base = base;                   // aliases Kb (dead after attn)
        mbase = base + 13*MiB;             // inside dead Kb, past GAT scratch
    } else {
        CXH1 = (bf16*)(base + 0*MiB);      // 16 MiB
        gat_base = base + 16*MiB;          // 9.5 MiB (no aliasing)
        Kb   = (bf16*)(base + 26*MiB);     // 0.5 MiB (one slice)
        Vtb  = (bf16*)(base + 26*MiB + 512u*1024u);
        mbase = base + 27*MiB;
    }
    float* Mw  = (float*)mbase;                         // 64 KB
    float* vkw = (float*)(mbase + 64*1024);             // 512 B
    float* vqw = (float*)(mbase + 64*1024 + 512);       // 512 B
    float* sbb = (float*)(mbase + 64*1024 + 1024);      // 4 B

    // GAT scratch: accumulators FIRST (contiguous zero region), then rest
    char* w = gat_base;
    auto alloc = [&](size_t bytes){ void* p = (void*)w; w += (bytes + 255) & ~(size_t)255; return p; };
    float* den1 = (float*)alloc((size_t)NNODE*NHEADS*sizeof(float));
    float* agg1 = (float*)alloc((size_t)NNODE*HID*sizeof(float));
    float* den2 = (float*)alloc((size_t)NNODE*sizeof(float));
    float* agg2 = (float*)alloc((size_t)NNODE*OUTCH*sizeof(float));
    char*  zend = w;
    bf16*  hw1  = (bf16*) alloc((size_t)NNODE*HID*sizeof(bf16));
    float* als1 = (float*)alloc((size_t)NNODE*NHEADS*sizeof(float));
    float* ald1 = (float*)alloc((size_t)NNODE*NHEADS*sizeof(float));
    bf16*  hw2  = (bf16*) alloc((size_t)NNODE*OUTCH*sizeof(bf16));
    float* als2 = (float*)alloc((size_t)NNODE*sizeof(float));
    float* ald2 = (float*)alloc((size_t)NNODE*sizeof(float));
    const int zero_n = (int)((zend - (char*)den1)/4);

    // ---- trunk ----
    if (wide){
        k_kv<<<PROWS, HID, 0, stream>>>(x, ln1g, ln1b, t_wk, t_bk, t_wv, t_bv, 0, Kb, Vtb);
        k_attn_mfma<<<dim3(BM, NTILE), 256, 0, stream>>>(x, Kb, Vtb, ln1g, ln1b,
                                                         t_wq, t_bq, 0, CXH1);
        k_h1<<<dim3(BM, NTILE), 256, 0, stream>>>(x, t_wo, skw, t_bo, skb, 0, CXH1);
    } else {
        for (int s = 0; s < BM; ++s){
            k_kv<<<NN, HID, 0, stream>>>(x, ln1g, ln1b, t_wk, t_bk, t_wv, t_bv, s*NN, Kb, Vtb);
            k_attn_mfma<<<dim3(1, NTILE), 256, 0, stream>>>(x, Kb, Vtb, ln1g, ln1b,
                                                            t_wq, t_bq, s, CXH1);
        }
        k_h1<<<dim3(BM, NTILE), 256, 0, stream>>>(x, t_wo, skw, t_bo, skb, 0, CXH1);
    }
    // precompute M/vk/vq/sbb + zero GAT accumulators (scratch dead/own region)
    k_prep<<<32, 256, 0, stream>>>(s_wq, s_wk, s_bq, s_bk, Mw, vkw, vqw, sbb,
                                   den1, zero_n);

    k_mix<<<NNODE/4, 512, 0, stream>>>(CXH1, ln2g, ln2b, Mw, vkw, vqw, sbb,
                                       s_bv, s_wv, s_wo, s_bo, ln3g, ln3b,
                                       w1, b1, w2, b2,
                                       g1w, g1as, g1ad, hw1, als1, ald1);

    k_gat_agg1<<<(NETOT*HID)/256, 256, 0, stream>>>(ei, als1, ald1, hw1, agg1, den1);
    k_gat2_lin<<<NNODE, OUTCH, 0, stream>>>(agg1, den1, g1b, g2w, g2as, g2ad,
                                            hw2, als2, ald2);
    k_gat_agg2<<<(NETOT*OUTCH)/256, 256, 0, stream>>>(ei, als2, ald2, hw2, agg2, den2);
    k_final<<<NNODE, OUTCH, 0, stream>>>(agg2, den2, g2b, ffw, ffb, out);
}

// Round 18
// 531.029 us; speedup vs baseline: 1.1891x; 1.1651x over previous
//
#include <hip/hip_runtime.h>
#include <hip/hip_bf16.h>
#include <stdint.h>

// ---------------------------------------------------------------------------
// PFGAT. R18: k_mix rewritten as MFMA kernel (16 nodes/block): six GEMV
// chains (z7@M, zbar@wv, cx2@wo, z3@w1, hl@w2, hn@g1w) become 16-row MFMA
// GEMMs against pre-transposed bf16 weights (built once in k_prep).
// LN2/softmax/LN3 elementwise with z2 recomputed from h1+stats.
// Rest of pipeline identical to R17.
// ---------------------------------------------------------------------------

#define BB     4
#define TT     8
#define NN     2048
#define FIN    16
#define HID    128
#define BM     (BB*TT)            // 32 attention slices
#define PROWS  (BM*NN)            // 65536 rows
#define NHEADS 4
#define OUTCH  64
#define OUTF   14
#define NEDGE  32768
#define NEDGEB (NEDGE*BB)         // 131072
#define NNODE  (BB*NN)            // 8192
#define NETOT  (NEDGEB + NNODE)   // 139264 (edges + self loops)

#define TQ     64                 // query tile (rows per block)
#define NTILE  (NN/TQ)            // 32 query tiles per slice

typedef __hip_bfloat16 bf16;
typedef __attribute__((ext_vector_type(8))) short bf16x8;   // MFMA A/B frag
typedef __attribute__((ext_vector_type(4))) float f32x4;    // MFMA C/D frag

__device__ __forceinline__ float b2f(bf16 v){ return __bfloat162float(v); }
__device__ __forceinline__ bf16  f2b(float f){ return __float2bfloat16(f); }

// ---------------------------------------------------------------------------
// K1: per row: LN1 over F=16 -> k,v projections; K row-major, V key-tiled.
// ---------------------------------------------------------------------------
__global__ void k_kv(const float* __restrict__ x,
                     const float* __restrict__ g1, const float* __restrict__ bb1,
                     const float* __restrict__ wk, const float* __restrict__ bk,
                     const float* __restrict__ wv, const float* __restrict__ bv,
                     int in_off, bf16* __restrict__ K, bf16* __restrict__ Vt)
{
    const int rloc = blockIdx.x;
    const int rin  = rloc + in_off;
    const int h = threadIdx.x;       // 0..127
    __shared__ float xr[FIN], lnv[FIN];
    if (h < FIN) xr[h] = x[(size_t)rin*FIN + h];
    __syncthreads();
    float mu = 0.f;
    #pragma unroll
    for (int f = 0; f < FIN; ++f) mu += xr[f];
    mu *= (1.f/FIN);
    float var = 0.f;
    #pragma unroll
    for (int f = 0; f < FIN; ++f){ float d = xr[f]-mu; var += d*d; }
    var *= (1.f/FIN);
    const float inv = rsqrtf(var + 1e-5f);
    if (h < FIN) lnv[h] = (xr[h]-mu)*inv*g1[h] + bb1[h];
    __syncthreads();
    float ak = bk[h], av = bv[h];
    #pragma unroll
    for (int f = 0; f < FIN; ++f){
        const float l = lnv[f];
        ak += l * wk[f*HID + h];
        av += l * wv[f*HID + h];
    }
    K[(size_t)rloc*HID + h] = f2b(ak);
    const int slice = rloc >> 11;            // 0 in narrow mode
    const int key   = rloc & (NN-1);
    Vt[(((size_t)slice*(NN/32) + (key>>5))*HID + h)*32 + (key&31)] = f2b(av);
}

// ---------------------------------------------------------------------------
// K2 (MFMA flash): unchanged.
// ---------------------------------------------------------------------------
__global__ __launch_bounds__(256)
void k_attn_mfma(const float* __restrict__ x,
                 const bf16* __restrict__ K, const bf16* __restrict__ Vt,
                 const float* __restrict__ g1, const float* __restrict__ bb1,
                 const float* __restrict__ wq, const float* __restrict__ bq,
                 int slice_off, bf16* __restrict__ CX)
{
    const int tile  = (NTILE-1) - (int)blockIdx.y;   // big tiles first
    const int q0    = tile*TQ;
    const int slice = blockIdx.x + slice_off;
    const int t     = threadIdx.x;
    const int w     = t >> 6;
    const int lane  = t & 63;
    const int quad  = lane >> 4;
    const int l16   = lane & 15;
    const int wr0   = w*16;

    __shared__ float xs [TQ][FIN];
    __shared__ bf16  Qs [TQ][136];
    __shared__ bf16  Ps [4][16][40];
    __shared__ bf16  Ks [32*136];
    __shared__ bf16  Vs [128*40];

    for (int u = t; u < TQ*FIN; u += 256)
        ((float*)xs)[u] = x[((size_t)slice*NN + q0)*FIN + u];
    __syncthreads();
    if (t < TQ){
        float mu = 0.f;
        #pragma unroll
        for (int f = 0; f < FIN; ++f) mu += xs[t][f];
        mu *= (1.f/FIN);
        float var = 0.f;
        #pragma unroll
        for (int f = 0; f < FIN; ++f){ float d = xs[t][f]-mu; var += d*d; }
        var *= (1.f/FIN);
        const float inv = rsqrtf(var + 1e-5f);
        #pragma unroll
        for (int f = 0; f < FIN; ++f)
            xs[t][f] = (xs[t][f]-mu)*inv*g1[f] + bb1[f];
    }
    __syncthreads();
    {
        const int ch = t & 127, half = t >> 7;
        const float scale = 0.08838834764831845f;
        float wqr[FIN];
        #pragma unroll
        for (int f = 0; f < FIN; ++f) wqr[f] = wq[f*HID + ch];
        const float bqv = bq[ch];
        for (int j = 0; j < 32; ++j){
            const int row = half*32 + j;
            const float4 l0 = ((const float4*)&xs[row][0])[0];
            const float4 l1 = ((const float4*)&xs[row][0])[1];
            const float4 l2 = ((const float4*)&xs[row][0])[2];
            const float4 l3 = ((const float4*)&xs[row][0])[3];
            float a = bqv;
            a += l0.x*wqr[0]  + l0.y*wqr[1]  + l0.z*wqr[2]  + l0.w*wqr[3];
            a += l1.x*wqr[4]  + l1.y*wqr[5]  + l1.z*wqr[6]  + l1.w*wqr[7];
            a += l2.x*wqr[8]  + l2.y*wqr[9]  + l2.z*wqr[10] + l2.w*wqr[11];
            a += l3.x*wqr[12] + l3.y*wqr[13] + l3.z*wqr[14] + l3.w*wqr[15];
            Qs[row][ch] = f2b(a*scale);
        }
    }
    __syncthreads();

    bf16x8 qf[4];
    #pragma unroll
    for (int ks = 0; ks < 4; ++ks)
        qf[ks] = *(const bf16x8*)(const void*)&Qs[wr0 + l16][ks*32 + quad*8];

    f32x4 O[8];
    #pragma unroll
    for (int ct = 0; ct < 8; ++ct) O[ct] = (f32x4){0.f,0.f,0.f,0.f};
    float l_[4] = {0.f,0.f,0.f,0.f};

    const size_t kb = (size_t)blockIdx.x * NN * HID;
    const size_t vb = (size_t)blockIdx.x * (size_t)(NN/32) * HID*32;
    const int jend_blk = q0 + TQ - 1;
    const int my_jmax  = q0 + wr0 + 15;
    const int brow = q0 + wr0 + quad*4;

    for (int j0 = 0; j0 <= jend_blk; j0 += 32){
        {
            const bf16* ksl = K  + kb + (size_t)j0*HID;
            const bf16* vsl = Vt + vb + (size_t)(j0>>5)*(HID*32);
            #pragma unroll
            for (int it = 0; it < 2; ++it){
                const int c = t + it*256;
                *(bf16x8*)(void*)&Ks[(c>>4)*136 + (c&15)*8] =
                    *(const bf16x8*)(const void*)(ksl + c*8);
                *(bf16x8*)(void*)&Vs[(c>>2)*40 + (c&3)*8] =
                    *(const bf16x8*)(const void*)(vsl + c*8);
            }
        }
        __syncthreads();

        if (j0 <= my_jmax){
            f32x4 S0 = (f32x4){0.f,0.f,0.f,0.f}, S1 = S0;
            #pragma unroll
            for (int ks = 0; ks < 4; ++ks){
                const bf16x8 kf0 = *(const bf16x8*)(const void*)
                    &Ks[(l16     )*136 + ks*32 + quad*8];
                const bf16x8 kf1 = *(const bf16x8*)(const void*)
                    &Ks[(l16 + 16)*136 + ks*32 + quad*8];
                S0 = __builtin_amdgcn_mfma_f32_16x16x32_bf16(qf[ks], kf0, S0, 0, 0, 0);
                S1 = __builtin_amdgcn_mfma_f32_16x16x32_bf16(qf[ks], kf1, S1, 0, 0, 0);
            }
            const int c0j = j0 + l16, c1j = c0j + 16;
            #pragma unroll
            for (int r = 0; r < 4; ++r){
                const float s0 = (c0j <= brow + r) ? S0[r] : -1e30f;
                const float s1 = (c1j <= brow + r) ? S1[r] : -1e30f;
                const bf16 hb0 = f2b(__expf(s0));
                const bf16 hb1 = f2b(__expf(s1));
                Ps[w][quad*4 + r][l16]      = hb0;
                Ps[w][quad*4 + r][l16 + 16] = hb1;
                l_[r] += b2f(hb0) + b2f(hb1);
            }
            const bf16x8 pf = *(const bf16x8*)(const void*)&Ps[w][l16][quad*8];
            #pragma unroll
            for (int ct = 0; ct < 8; ++ct){
                const bf16x8 vf = *(const bf16x8*)(const void*)
                    &Vs[(ct*16 + l16)*40 + quad*8];
                O[ct] = __builtin_amdgcn_mfma_f32_16x16x32_bf16(pf, vf, O[ct], 0, 0, 0);
            }
        }
        __syncthreads();
    }

    {
        float inv[4];
        #pragma unroll
        for (int r = 0; r < 4; ++r){
            float rs = l_[r];
            rs += __shfl_xor(rs, 1);
            rs += __shfl_xor(rs, 2);
            rs += __shfl_xor(rs, 4);
            rs += __shfl_xor(rs, 8);
            inv[r] = 1.f/rs;
        }
        #pragma unroll
        for (int ct = 0; ct < 8; ++ct)
        #pragma unroll
        for (int r = 0; r < 4; ++r)
            Qs[wr0 + quad*4 + r][ct*16 + l16] = f2b(O[ct][r]*inv[r]);
    }
    __syncthreads();
    {
        const int row = t >> 2, ch0 = (t & 3)*32;
        bf16* dst = CX + ((size_t)slice*NN + q0 + row)*HID + ch0;
        #pragma unroll
        for (int c = 0; c < 4; ++c)
            *(bf16x8*)(void*)(dst + c*8) =
                *(const bf16x8*)(const void*)&Qs[row][ch0 + c*8];
    }
}

// ---------------------------------------------------------------------------
// K_H1 (MFMA epilogue GEMM): unchanged.
// ---------------------------------------------------------------------------
__global__ __launch_bounds__(256)
void k_h1(const float* __restrict__ x,
          const float* __restrict__ t_wo, const float* __restrict__ skw,
          const float* __restrict__ t_bo, const float* __restrict__ skb,
          int slice_off, bf16* __restrict__ CXH1)
{
    const int slice = blockIdx.x + slice_off;
    const int q0    = blockIdx.y * TQ;
    const int t     = threadIdx.x;
    const int w     = t >> 6;
    const int lane  = t & 63;
    const int quad  = lane >> 4;
    const int l16   = lane & 15;
    const int wr0   = w*16;

    __shared__ bf16 Aext[TQ][168];
    __shared__ bf16 Bext[HID][168];

    {
        const bf16* src = CXH1 + ((size_t)slice*NN + q0)*HID;
        #pragma unroll
        for (int it = 0; it < 4; ++it){
            const int c = t + it*256;
            *(bf16x8*)(void*)&Aext[c>>4][(c&15)*8] =
                *(const bf16x8*)(const void*)(src + c*8);
        }
    }
    #pragma unroll
    for (int it = 0; it < 4; ++it){
        const int u = t + it*256;
        const int row = u >> 4, f = u & 15;
        Aext[row][128 + f] = f2b(x[((size_t)slice*NN + q0 + row)*FIN + f]);
    }
    #pragma unroll
    for (int it = 0; it < 4; ++it){
        const int u = t + it*256;
        Aext[u>>4][144 + (u&15)] = f2b(0.f);
    }
    #pragma unroll
    for (int it = 0; it < 16; ++it){
        const int idx = t + it*256;
        const int c = idx >> 5, ch4 = (idx & 31)*4;
        const float4 v = ((const float4*)t_wo)[idx];
        Bext[ch4+0][c] = f2b(v.x);
        Bext[ch4+1][c] = f2b(v.y);
        Bext[ch4+2][c] = f2b(v.z);
        Bext[ch4+3][c] = f2b(v.w);
    }
    #pragma unroll
    for (int it = 0; it < 2; ++it){
        const int idx = t + it*256;
        const int f = idx >> 5, ch4 = (idx & 31)*4;
        const float4 v = ((const float4*)skw)[idx];
        Bext[ch4+0][128+f] = f2b(v.x);
        Bext[ch4+1][128+f] = f2b(v.y);
        Bext[ch4+2][128+f] = f2b(v.z);
        Bext[ch4+3][128+f] = f2b(v.w);
    }
    #pragma unroll
    for (int it = 0; it < 8; ++it){
        const int u = t + it*256;
        Bext[u>>4][144 + (u&15)] = f2b(0.f);
    }
    __syncthreads();

    f32x4 O[8];
    #pragma unroll
    for (int ct = 0; ct < 8; ++ct) O[ct] = (f32x4){0.f,0.f,0.f,0.f};
    #pragma unroll
    for (int ks = 0; ks < 5; ++ks){
        const bf16x8 af = *(const bf16x8*)(const void*)&Aext[wr0 + l16][ks*32 + quad*8];
        #pragma unroll
        for (int ct = 0; ct < 8; ++ct){
            const bf16x8 bf = *(const bf16x8*)(const void*)&Bext[ct*16 + l16][ks*32 + quad*8];
            O[ct] = __builtin_amdgcn_mfma_f32_16x16x32_bf16(af, bf, O[ct], 0, 0, 0);
        }
    }
    #pragma unroll
    for (int ct = 0; ct < 8; ++ct){
        const int col = ct*16 + l16;
        const float bias = t_bo[col] + skb[col];
        #pragma unroll
        for (int r = 0; r < 4; ++r)
            Aext[wr0 + quad*4 + r][col] = f2b(O[ct][r] + bias);
    }
    __syncthreads();
    {
        const int row = t >> 2, ch0 = (t & 3)*32;
        bf16* dst = CXH1 + ((size_t)slice*NN + q0 + row)*HID + ch0;
        #pragma unroll
        for (int c = 0; c < 4; ++c)
            *(bf16x8*)(void*)(dst + c*8) =
                *(const bf16x8*)(const void*)&Aext[row][ch0 + c*8];
    }
}

// ---------------------------------------------------------------------------
// K_PREP: blocks 0-15: Mt[c][a] = s_wk[c].s_wq[a] (bf16, transposed bilinear);
// block 16: vk/vq/sbb; blocks 17-21: bf16 transposed weight copies;
// all 32 blocks zero the GAT accumulator region.
// ---------------------------------------------------------------------------
__global__ __launch_bounds__(256)
void k_prep(const float* __restrict__ s_wq, const float* __restrict__ s_wk,
            const float* __restrict__ bq, const float* __restrict__ bk,
            const float* __restrict__ s_wv, const float* __restrict__ s_wo,
            const float* __restrict__ g1w, const float* __restrict__ w1,
            const float* __restrict__ w2,
            bf16* __restrict__ Mt, bf16* __restrict__ wvT, bf16* __restrict__ woT,
            bf16* __restrict__ g1wT, bf16* __restrict__ w1T, bf16* __restrict__ w2T,
            float* __restrict__ vk, float* __restrict__ vq, float* __restrict__ sbb,
            float* __restrict__ zp, int zn)
{
    const int b = blockIdx.x;          // 0..31
    const int t = threadIdx.x;
    for (int u = b*256 + t; u < zn; u += 32*256) zp[u] = 0.f;
    __shared__ float wq_s[HID*HID];    // 64 KB
    __shared__ float wk_s[8][HID];
    if (b < 16){
        for (int u = t; u < HID*HID; u += 256) wq_s[u] = s_wq[u];
        for (int u = t; u < 8*HID;   u += 256) ((float*)wk_s)[u] = s_wk[b*8*HID + u];
        __syncthreads();
        #pragma unroll
        for (int i = 0; i < 4; ++i){
            const int e = t + i*256;
            const int cl = e >> 7, a = e & 127;     // Mt row c = b*8+cl, col a
            float acc = 0.f;
            for (int hh = 0; hh < HID; ++hh) acc += wk_s[cl][hh]*wq_s[a*HID + hh];
            Mt[(size_t)(b*8 + cl)*HID + a] = f2b(acc);
        }
    } else if (b == 16){
        if (t < HID){
            float a1 = 0.f, a2 = 0.f;
            for (int hh = 0; hh < HID; ++hh){
                a1 += bq[hh]*s_wk[t*HID + hh];
                a2 += s_wq[t*HID + hh]*bk[hh];
            }
            vk[t] = a1; vq[t] = a2;
            if (t == 0){
                float s = 0.f;
                for (int hh = 0; hh < HID; ++hh) s += bq[hh]*bk[hh];
                *sbb = s;
            }
        }
    } else if (b == 17){
        for (int u = t; u < HID*HID; u += 256){
            const int c = u >> 7, h = u & 127;
            wvT[h*HID + c] = f2b(s_wv[u]);
        }
    } else if (b == 18){
        for (int u = t; u < HID*HID; u += 256){
            const int c = u >> 7, h = u & 127;
            woT[h*HID + c] = f2b(s_wo[u]);
        }
    } else if (b == 19){
        for (int u = t; u < HID*HID; u += 256){
            const int c = u >> 7, h = u & 127;
            g1wT[h*HID + c] = f2b(g1w[u]);
        }
    } else if (b == 20){
        for (int u = t; u < HID*2*HID; u += 256){
            const int k = u >> 8, n = u & 255;
            w1T[n*HID + k] = f2b(w1[u]);
        }
    } else if (b == 21){
        for (int u = t; u < 2*HID*HID; u += 256){
            const int k = u >> 7, n = u & 127;
            w2T[(size_t)n*2*HID + k] = f2b(w2[u]);
        }
    }
}

// ---------------------------------------------------------------------------
// K3 (R18, MFMA): 16 nodes/block, 256 thr (4 waves). Six 16-row MFMA GEMMs
// + elementwise LN2/softmax/LN3 (z2 recomputed from h1 + stats).
// Emits hw1/als1/ald1 directly.
// ---------------------------------------------------------------------------
__global__ __launch_bounds__(256)
void k_mix(const bf16* __restrict__ H1,
           const float* __restrict__ ln2g, const float* __restrict__ ln2b,
           const bf16* __restrict__ Mt, const bf16* __restrict__ wvT,
           const bf16* __restrict__ woT, const bf16* __restrict__ g1wT,
           const bf16* __restrict__ w1T, const bf16* __restrict__ w2T,
           const float* __restrict__ vk, const float* __restrict__ vq,
           const float* __restrict__ sbbp,
           const float* __restrict__ s_bv, const float* __restrict__ s_bo,
           const float* __restrict__ bm1, const float* __restrict__ bm2,
           const float* __restrict__ ln3g, const float* __restrict__ ln3b,
           const float* __restrict__ g1as, const float* __restrict__ g1ad,
           bf16* __restrict__ hw1, float* __restrict__ als1, float* __restrict__ ald1)
{
    const int blk0 = blockIdx.x * 16;         // first node
    const int bb = blk0 >> 11, s0 = blk0 & (NN-1);
    const int t = threadIdx.x;
    const int w = t >> 6;
    const int lane = t & 63;
    const int quad = lane >> 4;
    const int l16  = lane & 15;

    __shared__ bf16  h1s[16][TT][136];   // 34816 B
    __shared__ bf16  ZA [16][136];       // 4352 B (A staging, reused)
    __shared__ bf16  HLs[16][264];       // 8448 B (MLP hidden)
    __shared__ float Cw [16][128];       // 8192 B (fp32 work)
    __shared__ float ln2gs[HID], ln2bs[HID];
    __shared__ float mu_s[16][TT], inv_s[16][TT];
    __shared__ float ps[16][TT];
    __shared__ float sbq_s[16], mu3[16], inv3[16];

    // ---- S1: stage h1 (bf16) + ln2 params ----
    for (int m = 0; m < TT; ++m){
        const bf16* src = H1 + ((size_t)(bb*TT + m)*NN + s0)*HID;
        const int node = t >> 4, c8 = t & 15;
        *(bf16x8*)(void*)&h1s[node][m][c8*8] =
            *(const bf16x8*)(const void*)(src + (size_t)node*HID + c8*8);
    }
    if (t < HID){ ln2gs[t] = ln2g[t]; ln2bs[t] = ln2b[t]; }
    __syncthreads();

    // ---- S2: LN2 stats (pair of threads per (node,m)) ----
    {
        const int idx = t >> 1, half = t & 1;
        const int node = idx >> 3, m = idx & 7;
        float sum = 0.f, sq = 0.f;
        for (int c = half; c < HID; c += 2){
            const float v = b2f(h1s[node][m][c]);
            sum += v; sq += v*v;
        }
        sum += __shfl_xor(sum, 1); sq += __shfl_xor(sq, 1);
        if (half == 0){
            const float mu = sum*(1.f/HID);
            const float var = sq*(1.f/HID) - mu*mu;
            mu_s[node][m] = mu;
            inv_s[node][m] = rsqrtf(var + 1e-5f);
        }
    }
    __syncthreads();

    // ---- S3: Z7 -> ZA; sbq partial ----
    #pragma unroll
    for (int i = 0; i < 8; ++i){
        const int idx = t + i*256;               // 2048
        const int n = idx >> 7, c = idx & 127;
        const float z = (b2f(h1s[n][7][c]) - mu_s[n][7])*inv_s[n][7]*ln2gs[c] + ln2bs[c];
        ZA[n][c] = f2b(z);
    }
    if (t < 128){
        const int node = t >> 3, l8 = t & 7;
        float sp = 0.f;
        for (int c = l8; c < HID; c += 8){
            const float z = (b2f(h1s[node][7][c]) - mu_s[node][7])*inv_s[node][7]*ln2gs[c] + ln2bs[c];
            sp += vq[c]*z;
        }
        sp += __shfl_xor(sp, 1);
        sp += __shfl_xor(sp, 2);
        sp += __shfl_xor(sp, 4);
        if (l8 == 0) sbq_s[node] = sp;
    }
    __syncthreads();

    // ---- S4: G1 rp = Z7@Mt + vk -> Cw ----
    {
        bf16x8 af[4];
        #pragma unroll
        for (int ks = 0; ks < 4; ++ks)
            af[ks] = *(const bf16x8*)(const void*)&ZA[l16][ks*32 + quad*8];
        __syncthreads();
        f32x4 C0 = (f32x4){0,0,0,0}, C1 = C0;
        #pragma unroll
        for (int ks = 0; ks < 4; ++ks){
            const bf16x8 b0 = *(const bf16x8*)(const void*)(Mt + (size_t)(w*32      + l16)*HID + ks*32 + quad*8);
            const bf16x8 b1 = *(const bf16x8*)(const void*)(Mt + (size_t)(w*32 + 16 + l16)*HID + ks*32 + quad*8);
            C0 = __builtin_amdgcn_mfma_f32_16x16x32_bf16(af[ks], b0, C0, 0, 0, 0);
            C1 = __builtin_amdgcn_mfma_f32_16x16x32_bf16(af[ks], b1, C1, 0, 0, 0);
        }
        const int c0 = w*32 + l16, c1 = c0 + 16;
        #pragma unroll
        for (int r = 0; r < 4; ++r){
            Cw[quad*4 + r][c0] = C0[r] + vk[c0];
            Cw[quad*4 + r][c1] = C1[r] + vk[c1];
        }
    }
    __syncthreads();

    // ---- S5: scr -> ps ----
    {
        const int idx = t >> 1, half = t & 1;
        const int node = idx >> 3, m = idx & 7;
        const float mu = mu_s[node][m], iv = inv_s[node][m];
        float d = 0.f;
        for (int c = half; c < HID; c += 2){
            const float z = (b2f(h1s[node][m][c]) - mu)*iv*ln2gs[c] + ln2bs[c];
            d += Cw[node][c]*z;
        }
        d += __shfl_xor(d, 1);
        if (half == 0)
            ps[node][m] = (d + sbq_s[node] + *sbbp) * 0.08838834764831845f;
    }
    __syncthreads();
    // ---- S6: softmax per node ----
    if (t < 16){
        float mx = -1e30f;
        #pragma unroll
        for (int m = 0; m < TT; ++m) mx = fmaxf(mx, ps[t][m]);
        float p[TT], se = 0.f;
        #pragma unroll
        for (int m = 0; m < TT; ++m){ p[m] = __expf(ps[t][m]-mx); se += p[m]; }
        const float isum = 1.f/se;
        #pragma unroll
        for (int m = 0; m < TT; ++m) ps[t][m] = p[m]*isum;
    }
    __syncthreads();
    // ---- S7: zbar -> ZA ----
    #pragma unroll
    for (int i = 0; i < 8; ++i){
        const int idx = t + i*256;
        const int n = idx >> 7, c = idx & 127;
        const float gc = ln2gs[c], bc = ln2bs[c];
        float acc = 0.f;
        #pragma unroll
        for (int m = 0; m < TT; ++m){
            const float z = (b2f(h1s[n][m][c]) - mu_s[n][m])*inv_s[n][m]*gc + bc;
            acc += ps[n][m]*z;
        }
        ZA[n][c] = f2b(acc);
    }
    __syncthreads();

    // ---- S8: G2 cx2 = ZB@wvT + bv -> ZA ----
    {
        bf16x8 af[4];
        #pragma unroll
        for (int ks = 0; ks < 4; ++ks)
            af[ks] = *(const bf16x8*)(const void*)&ZA[l16][ks*32 + quad*8];
        __syncthreads();
        f32x4 C0 = (f32x4){0,0,0,0}, C1 = C0;
        #pragma unroll
        for (int ks = 0; ks < 4; ++ks){
            const bf16x8 b0 = *(const bf16x8*)(const void*)(wvT + (size_t)(w*32      + l16)*HID + ks*32 + quad*8);
            const bf16x8 b1 = *(const bf16x8*)(const void*)(wvT + (size_t)(w*32 + 16 + l16)*HID + ks*32 + quad*8);
            C0 = __builtin_amdgcn_mfma_f32_16x16x32_bf16(af[ks], b0, C0, 0, 0, 0);
            C1 = __builtin_amdgcn_mfma_f32_16x16x32_bf16(af[ks], b1, C1, 0, 0, 0);
        }
        const int c0 = w*32 + l16, c1 = c0 + 16;
        #pragma unroll
        for (int r = 0; r < 4; ++r){
            ZA[quad*4 + r][c0] = f2b(C0[r] + s_bv[c0]);
            ZA[quad*4 + r][c1] = f2b(C1[r] + s_bv[c1]);
        }
    }
    __syncthreads();

    // ---- S9: G3 h2 = cx2@woT + bo + h1[7] -> Cw ----
    {
        bf16x8 af[4];
        #pragma unroll
        for (int ks = 0; ks < 4; ++ks)
            af[ks] = *(const bf16x8*)(const void*)&ZA[l16][ks*32 + quad*8];
        __syncthreads();
        f32x4 C0 = (f32x4){0,0,0,0}, C1 = C0;
        #pragma unroll
        for (int ks = 0; ks < 4; ++ks){
            const bf16x8 b0 = *(const bf16x8*)(const void*)(woT + (size_t)(w*32      + l16)*HID + ks*32 + quad*8);
            const bf16x8 b1 = *(const bf16x8*)(const void*)(woT + (size_t)(w*32 + 16 + l16)*HID + ks*32 + quad*8);
            C0 = __builtin_amdgcn_mfma_f32_16x16x32_bf16(af[ks], b0, C0, 0, 0, 0);
            C1 = __builtin_amdgcn_mfma_f32_16x16x32_bf16(af[ks], b1, C1, 0, 0, 0);
        }
        const int c0 = w*32 + l16, c1 = c0 + 16;
        #pragma unroll
        for (int r = 0; r < 4; ++r){
            const int node = quad*4 + r;
            Cw[node][c0] = C0[r] + s_bo[c0] + b2f(h1s[node][7][c0]);
            Cw[node][c1] = C1[r] + s_bo[c1] + b2f(h1s[node][7][c1]);
        }
    }
    __syncthreads();

    // ---- S10: LN3 stats (16-lane group per node) ----
    {
        const int node = t >> 4, part = t & 15;
        float sum = 0.f, sq = 0.f;
        for (int c = part; c < HID; c += 16){
            const float v = Cw[node][c];
            sum += v; sq += v*v;
        }
        sum += __shfl_xor(sum, 1); sq += __shfl_xor(sq, 1);
        sum += __shfl_xor(sum, 2); sq += __shfl_xor(sq, 2);
        sum += __shfl_xor(sum, 4); sq += __shfl_xor(sq, 4);
        sum += __shfl_xor(sum, 8); sq += __shfl_xor(sq, 8);
        if (part == 0){
            const float mu = sum*(1.f/HID);
            const float var = sq*(1.f/HID) - mu*mu;
            mu3[node] = mu;
            inv3[node] = rsqrtf(var + 1e-5f);
        }
    }
    __syncthreads();
    // ---- S11: z3 -> ZA ----
    #pragma unroll
    for (int i = 0; i < 8; ++i){
        const int idx = t + i*256;
        const int n = idx >> 7, c = idx & 127;
        ZA[n][c] = f2b((Cw[n][c] - mu3[n])*inv3[n]*ln3g[c] + ln3b[c]);
    }
    __syncthreads();

    // ---- S12: G4 hl = relu(z3@w1T + b1) -> HLs (ncols 256) ----
    {
        bf16x8 af[4];
        #pragma unroll
        for (int ks = 0; ks < 4; ++ks)
            af[ks] = *(const bf16x8*)(const void*)&ZA[l16][ks*32 + quad*8];
        __syncthreads();
        f32x4 C[4];
        #pragma unroll
        for (int u = 0; u < 4; ++u) C[u] = (f32x4){0,0,0,0};
        #pragma unroll
        for (int ks = 0; ks < 4; ++ks){
            #pragma unroll
            for (int u = 0; u < 4; ++u){
                const bf16x8 bfv = *(const bf16x8*)(const void*)
                    (w1T + (size_t)(w*64 + u*16 + l16)*HID + ks*32 + quad*8);
                C[u] = __builtin_amdgcn_mfma_f32_16x16x32_bf16(af[ks], bfv, C[u], 0, 0, 0);
            }
        }
        #pragma unroll
        for (int u = 0; u < 4; ++u){
            const int col = w*64 + u*16 + l16;
            const float bias = bm1[col];
            #pragma unroll
            for (int r = 0; r < 4; ++r)
                HLs[quad*4 + r][col] = f2b(fmaxf(C[u][r] + bias, 0.f));
        }
    }
    __syncthreads();

    // ---- S13: G5 hn = hl@w2T + b2 + h2 -> ZA (k=256) ----
    {
        bf16x8 af[8];
        #pragma unroll
        for (int ks = 0; ks < 8; ++ks)
            af[ks] = *(const bf16x8*)(const void*)&HLs[l16][ks*32 + quad*8];
        __syncthreads();
        f32x4 C0 = (f32x4){0,0,0,0}, C1 = C0;
        #pragma unroll
        for (int ks = 0; ks < 8; ++ks){
            const bf16x8 b0 = *(const bf16x8*)(const void*)(w2T + (size_t)(w*32      + l16)*2*HID + ks*32 + quad*8);
            const bf16x8 b1 = *(const bf16x8*)(const void*)(w2T + (size_t)(w*32 + 16 + l16)*2*HID + ks*32 + quad*8);
            C0 = __builtin_amdgcn_mfma_f32_16x16x32_bf16(af[ks], b0, C0, 0, 0, 0);
            C1 = __builtin_amdgcn_mfma_f32_16x16x32_bf16(af[ks], b1, C1, 0, 0, 0);
        }
        const int c0 = w*32 + l16, c1 = c0 + 16;
        #pragma unroll
        for (int r = 0; r < 4; ++r){
            const int node = quad*4 + r;
            ZA[node][c0] = f2b(C0[r] + bm2[c0] + Cw[node][c0]);
            ZA[node][c1] = f2b(C1[r] + bm2[c1] + Cw[node][c1]);
        }
    }
    __syncthreads();

    // ---- S14: G6 a = hn@g1wT -> Cw ----
    {
        bf16x8 af[4];
        #pragma unroll
        for (int ks = 0; ks < 4; ++ks)
            af[ks] = *(const bf16x8*)(const void*)&ZA[l16][ks*32 + quad*8];
        __syncthreads();
        f32x4 C0 = (f32x4){0,0,0,0}, C1 = C0;
        #pragma unroll
        for (int ks = 0; ks < 4; ++ks){
            const bf16x8 b0 = *(const bf16x8*)(const void*)(g1wT + (size_t)(w*32      + l16)*HID + ks*32 + quad*8);
            const bf16x8 b1 = *(const bf16x8*)(const void*)(g1wT + (size_t)(w*32 + 16 + l16)*HID + ks*32 + quad*8);
            C0 = __builtin_amdgcn_mfma_f32_16x16x32_bf16(af[ks], b0, C0, 0, 0, 0);
            C1 = __builtin_amdgcn_mfma_f32_16x16x32_bf16(af[ks], b1, C1, 0, 0, 0);
        }
        const int c0 = w*32 + l16, c1 = c0 + 16;
        #pragma unroll
        for (int r = 0; r < 4; ++r){
            Cw[quad*4 + r][c0] = C0[r];
            Cw[quad*4 + r][c1] = C1[r];
        }
    }
    __syncthreads();

    // ---- S15: outputs ----
    #pragma unroll
    for (int i = 0; i < 8; ++i){
        const int idx = t + i*256;                // node*128 + c
        hw1[(size_t)blk0*HID + idx] = f2b(((const float*)Cw)[idx]);
    }
    if (t < 64){
        const int node = t >> 2, hd = t & 3;
        float s1 = 0.f, s2 = 0.f;
        for (int j = 0; j < 32; ++j){
            const int c = hd*32 + j;
            const float a = Cw[node][c];
            s1 += a*g1as[c];
            s2 += a*g1ad[c];
        }
        als1[(blk0 + node)*NHEADS + hd] = s1;
        ald1[(blk0 + node)*NHEADS + hd] = s2;
    }
}

// ---------------------------------------------------------------------------
// GAT aggregation (unchanged from R17)
// ---------------------------------------------------------------------------
__device__ __forceinline__ void edge_decode(const int* __restrict__ ei, int e,
                                            int& src, int& dst, bool& dropped)
{
    if (e < NEDGEB){
        const int bb = e >> 15, k = e & (NEDGE-1);
        const int s0 = ei[k], d0 = ei[NEDGE + k];
        src = s0 + bb*NN; dst = d0 + bb*NN;
        dropped = (s0 == d0);
    } else { src = dst = e - NEDGEB; dropped = false; }
}

__global__ void k_gat_agg1(const int* __restrict__ ei, const float* __restrict__ als,
                           const float* __restrict__ ald, const bf16* __restrict__ hw,
                           float* __restrict__ agg, float* __restrict__ den)
{
    const int t = blockIdx.x*blockDim.x + threadIdx.x;   // NETOT*128
    const int e = t >> 7, c = t & 127;
    if (e >= NETOT) return;
    int src, dst; bool drop;
    edge_decode(ei, e, src, dst, drop);
    if (drop) return;
    const int hd = c >> 5;
    float a = als[src*NHEADS + hd] + ald[dst*NHEADS + hd];
    a = a > 0.f ? a : 0.2f*a;
    const float ex = __expf(a);
    atomicAdd(&agg[(size_t)dst*HID + c], ex * b2f(hw[(size_t)src*HID + c]));
    if ((c & 31) == 0) atomicAdd(&den[dst*NHEADS + hd], ex);
}

__global__ void k_gat2_lin(const float* __restrict__ agg1, const float* __restrict__ den1,
                           const float* __restrict__ g1b,
                           const float* __restrict__ W,
                           const float* __restrict__ asrc, const float* __restrict__ adst,
                           bf16* __restrict__ hw2, float* __restrict__ al2s, float* __restrict__ al2d)
{
    const int nid = blockIdx.x, c = threadIdx.x;    // 64 threads = 1 wave
    __shared__ float hr[HID];
    {
        const float v0 = agg1[(size_t)nid*HID + c]      / den1[nid*NHEADS + (c>>5)]      + g1b[c];
        const float v1 = agg1[(size_t)nid*HID + c + 64] / den1[nid*NHEADS + ((c+64)>>5)] + g1b[c+64];
        hr[c]    = v0 > 0.f ? v0 : expm1f(v0);
        hr[c+64] = v1 > 0.f ? v1 : expm1f(v1);
    }
    __syncthreads();
    float a = 0.f;
    for (int k = 0; k < HID; ++k) a += hr[k]*W[k*OUTCH + c];
    hw2[(size_t)nid*OUTCH + c] = f2b(a);
    float s1 = a*asrc[c], s2 = a*adst[c];
    #pragma unroll
    for (int off = 32; off > 0; off >>= 1){
        s1 += __shfl_down(s1, off);
        s2 += __shfl_down(s2, off);
    }
    if (c == 0){ al2s[nid] = s1; al2d[nid] = s2; }
}

__global__ void k_gat_agg2(const int* __restrict__ ei, const float* __restrict__ als,
                           const float* __restrict__ ald, const bf16* __restrict__ hw2,
                           float* __restrict__ agg, float* __restrict__ den)
{
    const int t = blockIdx.x*blockDim.x + threadIdx.x;   // NETOT*64
    const int e = t >> 6, c = t & 63;
    if (e >= NETOT) return;
    int src, dst; bool drop;
    edge_decode(ei, e, src, dst, drop);
    if (drop) return;
    float a = als[src] + ald[dst];
    a = a > 0.f ? a : 0.2f*a;
    const float ex = __expf(a);
    atomicAdd(&agg[(size_t)dst*OUTCH + c], ex * b2f(hw2[(size_t)src*OUTCH + c]));
    if (c == 0) atomicAdd(&den[dst], ex);
}

__global__ void k_final(const float* __restrict__ agg2, const float* __restrict__ den2,
                        const float* __restrict__ g2b,
                        const float* __restrict__ fw, const float* __restrict__ fb,
                        float* __restrict__ out)
{
    const int nid = blockIdx.x, c = threadIdx.x;    // 64
    __shared__ float g[OUTCH];
    g[c] = agg2[(size_t)nid*OUTCH + c]/den2[nid] + g2b[c];
    __syncthreads();
    if (c < OUTF){
        float o = fb[c];
        for (int k = 0; k < OUTCH; ++k) o += g[k]*fw[k*OUTF + c];
        const int b = nid >> 11, n = nid & (NN-1);
        out[((size_t)b*OUTF + c)*NN + n] = o;
    }
}

// ---------------------------------------------------------------------------
extern "C" void kernel_launch(void* const* d_in, const int* in_sizes, int n_in,
                              void* d_out, int out_size, void* d_ws, size_t ws_size,
                              hipStream_t stream)
{
    const float* x    = (const float*)d_in[0];
    const int*  ei    = (const int*)d_in[1];
    const float* ln1g = (const float*)d_in[2];  const float* ln1b = (const float*)d_in[3];
    const float* t_wq = (const float*)d_in[4];  const float* t_bq = (const float*)d_in[5];
    const float* t_wk = (const float*)d_in[6];  const float* t_bk = (const float*)d_in[7];
    const float* t_wv = (const float*)d_in[8];  const float* t_bv = (const float*)d_in[9];
    const float* t_wo = (const float*)d_in[10]; const float* t_bo = (const float*)d_in[11];
    const float* skw  = (const float*)d_in[12]; const float* skb  = (const float*)d_in[13];
    const float* ln2g = (const float*)d_in[14]; const float* ln2b = (const float*)d_in[15];
    const float* s_wq = (const float*)d_in[16]; const float* s_bq = (const float*)d_in[17];
    const float* s_wk = (const float*)d_in[18]; const float* s_bk = (const float*)d_in[19];
    const float* s_wv = (const float*)d_in[20]; const float* s_bv = (const float*)d_in[21];
    const float* s_wo = (const float*)d_in[22]; const float* s_bo = (const float*)d_in[23];
    const float* ln3g = (const float*)d_in[24]; const float* ln3b = (const float*)d_in[25];
    const float* w1   = (const float*)d_in[26]; const float* b1   = (const float*)d_in[27];
    const float* w2   = (const float*)d_in[28]; const float* b2   = (const float*)d_in[29];
    const float* g1w  = (const float*)d_in[30];
    const float* g1as = (const float*)d_in[31]; const float* g1ad = (const float*)d_in[32];
    const float* g1b  = (const float*)d_in[33];
    const float* g2w  = (const float*)d_in[34];
    const float* g2as = (const float*)d_in[35]; const float* g2ad = (const float*)d_in[36];
    const float* g2b  = (const float*)d_in[37];
    const float* ffw  = (const float*)d_in[38]; const float* ffb  = (const float*)d_in[39];
    float* out = (float*)d_out;

    const size_t MiB = 1024u*1024u;
    const bool wide = ws_size >= 48*MiB;

    char* base = (char*)d_ws;
    bf16 *Kb, *Vtb, *CXH1;
    char* gat_base;
    char* mbase;
    if (wide){
        Kb   = (bf16*)(base + 0*MiB);      // 16 MiB
        Vtb  = (bf16*)(base + 16*MiB);     // 16 MiB
        CXH1 = (bf16*)(base + 32*MiB);     // 16 MiB
        gat_base = base;                   // aliases Kb (dead after attn)
        mbase = base + 13*MiB;             // inside dead Kb, past GAT scratch
    } else {
        CXH1 = (bf16*)(base + 0*MiB);      // 16 MiB
        gat_base = base + 16*MiB;          // ~9.5 MiB (no aliasing)
        Kb   = (bf16*)(base + 26*MiB);     // 0.5 MiB (one slice)
        Vtb  = (bf16*)(base + 26*MiB + 512u*1024u);
        mbase = base + 27*MiB;
    }
    bf16*  Mt   = (bf16*)mbase;                       // 32 KB
    bf16*  wvT  = (bf16*)(mbase + 32*1024);           // 32 KB
    bf16*  woT  = (bf16*)(mbase + 64*1024);           // 32 KB
    bf16*  g1wT = (bf16*)(mbase + 96*1024);           // 32 KB
    bf16*  w1T  = (bf16*)(mbase + 128*1024);          // 64 KB
    bf16*  w2T  = (bf16*)(mbase + 192*1024);          // 64 KB
    float* vkw  = (float*)(mbase + 256*1024);         // 512 B
    float* vqw  = (float*)(mbase + 256*1024 + 512);   // 512 B
    float* sbb  = (float*)(mbase + 256*1024 + 1024);  // 4 B

    // GAT scratch: accumulators FIRST (contiguous zero region), then rest
    char* w = gat_base;
    auto alloc = [&](size_t bytes){ void* p = (void*)w; w += (bytes + 255) & ~(size_t)255; return p; };
    float* den1 = (float*)alloc((size_t)NNODE*NHEADS*sizeof(float));
    float* agg1 = (float*)alloc((size_t)NNODE*HID*sizeof(float));
    float* den2 = (float*)alloc((size_t)NNODE*sizeof(float));
    float* agg2 = (float*)alloc((size_t)NNODE*OUTCH*sizeof(float));
    char*  zend = w;
    bf16*  hw1  = (bf16*) alloc((size_t)NNODE*HID*sizeof(bf16));
    float* als1 = (float*)alloc((size_t)NNODE*NHEADS*sizeof(float));
    float* ald1 = (float*)alloc((size_t)NNODE*NHEADS*sizeof(float));
    bf16*  hw2  = (bf16*) alloc((size_t)NNODE*OUTCH*sizeof(bf16));
    float* als2 = (float*)alloc((size_t)NNODE*sizeof(float));
    float* ald2 = (float*)alloc((size_t)NNODE*sizeof(float));
    const int zero_n = (int)((zend - (char*)den1)/4);

    // ---- trunk ----
    if (wide){
        k_kv<<<PROWS, HID, 0, stream>>>(x, ln1g, ln1b, t_wk, t_bk, t_wv, t_bv, 0, Kb, Vtb);
        k_attn_mfma<<<dim3(BM, NTILE), 256, 0, stream>>>(x, Kb, Vtb, ln1g, ln1b,
                                                         t_wq, t_bq, 0, CXH1);
        k_h1<<<dim3(BM, NTILE), 256, 0, stream>>>(x, t_wo, skw, t_bo, skb, 0, CXH1);
    } else {
        for (int s = 0; s < BM; ++s){
            k_kv<<<NN, HID, 0, stream>>>(x, ln1g, ln1b, t_wk, t_bk, t_wv, t_bv, s*NN, Kb, Vtb);
            k_attn_mfma<<<dim3(1, NTILE), 256, 0, stream>>>(x, Kb, Vtb, ln1g, ln1b,
                                                            t_wq, t_bq, s, CXH1);
        }
        k_h1<<<dim3(BM, NTILE), 256, 0, stream>>>(x, t_wo, skw, t_bo, skb, 0, CXH1);
    }
    k_prep<<<32, 256, 0, stream>>>(s_wq, s_wk, s_bq, s_bk, s_wv, s_wo, g1w, w1, w2,
                                   Mt, wvT, woT, g1wT, w1T, w2T,
                                   vkw, vqw, sbb, den1, zero_n);

    k_mix<<<NNODE/16, 256, 0, stream>>>(CXH1, ln2g, ln2b, Mt, wvT, woT, g1wT, w1T, w2T,
                                        vkw, vqw, sbb, s_bv, s_bo, b1, b2,
                                        ln3g, ln3b, g1as, g1ad, hw1, als1, ald1);

    k_gat_agg1<<<(NETOT*HID)/256, 256, 0, stream>>>(ei, als1, ald1, hw1, agg1, den1);
    k_gat2_lin<<<NNODE, OUTCH, 0, stream>>>(agg1, den1, g1b, g2w, g2as, g2ad,
                                            hw2, als2, ald2);
    k_gat_agg2<<<(NETOT*OUTCH)/256, 256, 0, stream>>>(ei, als2, ald2, hw2, agg2, den2);
    k_final<<<NNODE, OUTCH, 0, stream>>>(agg2, den2, g2b, ffw, ffb, out);
}